// Round 1
// 701.874 us; speedup vs baseline: 1.0563x; 1.0563x over previous
//
#include <hip/hip_runtime.h>
#include <math.h>

namespace {

typedef _Float16 half8v __attribute__((ext_vector_type(8)));
typedef _Float16 half4v __attribute__((ext_vector_type(4)));
typedef float    floatx4 __attribute__((ext_vector_type(4)));

constexpr int B   = 8;
constexpr int C   = 256;
constexpr int NH  = 4;
constexpr int HD  = 64;
constexpr int NWIN = 400;   // 20x20 windows per level
constexpr int NT  = 35;     // 25 + 9 + 1 tokens per window
constexpr int QKVN = 768;
constexpr int RPB = NWIN * NT;  // 14,000 token-rows per batch

// per-batch byte counts for workspace
constexpr size_t QKV_B  = (size_t)8400 * QKVN * 2;   // 12,902,400  (f16)
constexpr size_t OATT_B = (size_t)RPB * C * 2;       //  7,168,000  (f16)
constexpr size_t YT_B   = (size_t)RPB * C * 4;       // 14,336,000  (f32)
constexpr size_t PB_B   = QKV_B + OATT_B + YT_B;     // 34,406,400
constexpr size_t POS_B  = 19712;                     // 4900 f32, padded

__device__ inline unsigned pack2(float a, float b) {
  union { _Float16 h[2]; unsigned u; } x;
  x.h[0] = (_Float16)a; x.h[1] = (_Float16)b;
  return x.u;
}

// ---------------- pos table ----------------
__device__ inline void token_coord(int j, double& cy, double& cx) {
  if (j < 25)      { int ty = j / 5,  tx = j % 5;  cy = (double)(ty - 2); cx = (double)(tx - 2); }
  else if (j < 34) { int t = j - 25; int ty = t / 3, tx = t % 3;
                     cy = (double)(ty - 1) * (5.0 / 3.0); cx = (double)(tx - 1) * (5.0 / 3.0); }
  else             { cy = 0.0; cx = 0.0; }
}

__global__ void pos_kernel(const float* __restrict__ rpb, const float* __restrict__ ab,
                           float* __restrict__ pos) {
  int p = blockIdx.x * blockDim.x + threadIdx.x;
  if (p >= NH * NT * NT) return;
  int j = p % NT, i = (p / NT) % NT, h = p / (NT * NT);
  double cyi, cxi, cyj, cxj;
  token_coord(i, cyi, cxi);
  token_coord(j, cyj, cxj);
  float fidx = (float)(((cyi - cyj) + 4.0) * 9.0 + ((cxi - cxj) + 4.0));
  int fl = min(max((int)floorf(fidx), 0), 80);
  int ce = min(max((int)ceilf(fidx), 0), 80);
  float w = fidx - (float)fl;
  float pv = (1.0f - w) * rpb[fl * NH + h] + w * rpb[ce * NH + h];
  int li = (i < 25) ? 0 : ((i < 34) ? 1 : 2);
  pos[p] = pv + ab[li * NH + h];
}

// ---------------- QKV GEMM (f16 MFMA, 128x128 tile): Y[m, 768](f16) = X^T @ W ----------------
// Epilogue: L2-normalize each output row per 64-col head section when n0 < normN (q,k).
__global__ __launch_bounds__(256) void qkv_gemm(const float* __restrict__ X,
                                                const float* __restrict__ W,
                                                _Float16* __restrict__ Y,
                                                int HW, int Mg, int normN) {
  __shared__ _Float16 As[128][40];   // row 80B, 16B-aligned frag reads
  __shared__ _Float16 Bs[128][40];
  const int tid  = threadIdx.x;
  const int m0   = blockIdx.x * 128;
  const int n0   = blockIdx.y * 128;
  const int w    = tid >> 6;
  const int lane = tid & 63;
  const int quad = lane >> 4;
  const int mn   = lane & 15;

  floatx4 acc[2][8] = {};
  for (int k0 = 0; k0 < C; k0 += 32) {
    // stage A: transpose (column-major global -> row-major LDS), f16x2 packed writes
#pragma unroll
    for (int u = 0; u < 2; ++u) {
      int unit = u * 256 + tid;        // 512 units: 32 m-quads x 16 k-pairs
      int mq = unit & 31, kp = unit >> 5;
      int mb = 4 * mq;
      int gm = m0 + mb;
      if (gm + 3 < Mg) {
        int bb = gm / HW; int pix = gm - bb * HW;
        const float* xp = X + ((size_t)bb * C + (k0 + 2 * kp)) * HW + pix;
        floatx4 va = *(const floatx4*)xp;
        floatx4 vb = *(const floatx4*)(xp + HW);
#pragma unroll
        for (int i = 0; i < 4; ++i) *(unsigned*)&As[mb + i][2 * kp] = pack2(va[i], vb[i]);
      } else {
#pragma unroll
        for (int i = 0; i < 4; ++i) {
          int g = min(gm + i, Mg - 1);
          int bb = g / HW; int pix = g - bb * HW;
          const float* xp = X + ((size_t)bb * C + (k0 + 2 * kp)) * HW + pix;
          *(unsigned*)&As[mb + i][2 * kp] = pack2(xp[0], xp[HW]);
        }
      }
    }
    // stage B: W row-major (K x 768), 128 cols
#pragma unroll
    for (int u = 0; u < 2; ++u) {
      int e = u * 256 + tid;           // 512 units: 32 n-quads x 16 k-pairs
      int nq = e & 31, kp = e >> 5;
      const float* wp = W + (size_t)(k0 + 2 * kp) * QKVN + n0 + 4 * nq;
      floatx4 va = *(const floatx4*)wp;
      floatx4 vb = *(const floatx4*)(wp + QKVN);
#pragma unroll
      for (int i = 0; i < 4; ++i) *(unsigned*)&Bs[4 * nq + i][2 * kp] = pack2(va[i], vb[i]);
    }
    __syncthreads();
    half8v a0 = *(const half8v*)&As[w * 32 + mn][quad * 8];
    half8v a1 = *(const half8v*)&As[w * 32 + 16 + mn][quad * 8];
#pragma unroll
    for (int ni = 0; ni < 8; ++ni) {
      half8v bf = *(const half8v*)&Bs[ni * 16 + mn][quad * 8];
      acc[0][ni] = __builtin_amdgcn_mfma_f32_16x16x32_f16(a0, bf, acc[0][ni], 0, 0, 0);
      acc[1][ni] = __builtin_amdgcn_mfma_f32_16x16x32_f16(a1, bf, acc[1][ni], 0, 0, 0);
    }
    __syncthreads();
  }

  // epilogue: per-row L2 norm per 64-col head section (two sections per 128-tile)
  const bool do_norm = (n0 < normN);
#pragma unroll
  for (int mi = 0; mi < 2; ++mi) {
#pragma unroll
    for (int r = 0; r < 4; ++r) {
      float s0 = 0.f, s1 = 0.f;
#pragma unroll
      for (int ni = 0; ni < 4; ++ni) { float vv = acc[mi][ni][r]; s0 += vv * vv; }
#pragma unroll
      for (int ni = 4; ni < 8; ++ni) { float vv = acc[mi][ni][r]; s1 += vv * vv; }
      s0 += __shfl_xor(s0, 1); s1 += __shfl_xor(s1, 1);
      s0 += __shfl_xor(s0, 2); s1 += __shfl_xor(s1, 2);
      s0 += __shfl_xor(s0, 4); s1 += __shfl_xor(s1, 4);
      s0 += __shfl_xor(s0, 8); s1 += __shfl_xor(s1, 8);
      float sc0 = do_norm ? (1.f / fmaxf(sqrtf(s0), 1e-12f)) : 1.f;
      float sc1 = do_norm ? (1.f / fmaxf(sqrtf(s1), 1e-12f)) : 1.f;
      int row = m0 + w * 32 + mi * 16 + quad * 4 + r;
      if (row < Mg) {
#pragma unroll
        for (int ni = 0; ni < 8; ++ni)
          Y[(size_t)row * QKVN + n0 + ni * 16 + mn] =
              (_Float16)(acc[mi][ni][r] * (ni < 4 ? sc0 : sc1));
      }
    }
  }
}

// ---------------- attention: MFMA version. Block = (b_local, window); wave = head. ----------------
// Scores: 48x48 (35 real tokens, padded) via mfma_f32_16x16x32_f16; Q/K fragments loaded
// directly from global (frag layout = 16 token-rows x 8 contiguous dims). V staged transposed
// in LDS for the PV B-operand; P staged f16 in LDS to shuffle C-layout -> A-frag layout.
// Padding tokens (out of image) keep K=0 => score = 0 + pos (still in softmax denom, matches
// reference). Tile-pad tokens (j>=35) masked to -inf. Waves are head-independent: no barriers.
__device__ inline const _Float16* token_row_ptr(int j, int wy, int wx, int b,
                                                const _Float16* q0, const _Float16* q1,
                                                const _Float16* q2) {
  if (j >= NT) return nullptr;
  int k_, s_, p_, Hl, t; const _Float16* base;
  if (j < 25)      { k_ = 5; s_ = 4; p_ = 2; Hl = 80; t = j;      base = q0; }
  else if (j < 34) { k_ = 3; s_ = 2; p_ = 1; Hl = 40; t = j - 25; base = q1; }
  else             { k_ = 1; s_ = 1; p_ = 0; Hl = 20; t = 0;      base = q2; }
  int ty = t / k_, tx = t % k_;
  int y = wy * s_ + ty - p_;
  int x = wx * s_ + tx - p_;
  if ((unsigned)y >= (unsigned)Hl || (unsigned)x >= (unsigned)Hl) return nullptr;
  return base + ((size_t)b * Hl * Hl + (size_t)y * Hl + x) * QKVN;
}

__global__ __launch_bounds__(256) void attn_kernel(const _Float16* __restrict__ qkv0,
                                                   const _Float16* __restrict__ qkv1,
                                                   const _Float16* __restrict__ qkv2,
                                                   const float* __restrict__ pos,
                                                   _Float16* __restrict__ O) {
  const int blk = blockIdx.x;               // b*NWIN + w
  const int w   = blk % NWIN;
  const int b   = blk / NWIN;
  const int wy = w / 20, wx = w % 20;
  const int tid  = threadIdx.x;
  const int h    = tid >> 6;                // wave = head
  const int lane = tid & 63;
  const int i16  = lane & 15;
  const int q4   = lane >> 4;

  // rows padded to 56 halfs (112 B): 16B-aligned frag reads, 2-way bank alias (free)
  __shared__ _Float16 vst[NH][64][56];      // V transposed: [d][j], j zero-padded to 48
  __shared__ _Float16 ps [NH][48][56];      // P (f16) [i][j]

  // --- stage V transposed (lane = d); j >= NT or invalid token -> 0
  for (int j = 0; j < 48; ++j) {
    _Float16 val = (_Float16)0.f;
    if (j < NT) {
      const _Float16* rp = token_row_ptr(j, wy, wx, b, qkv0, qkv1, qkv2);
      if (rp) val = rp[512 + h * HD + lane];
    }
    vst[h][lane][j] = val;
  }

  // --- Q/K fragments direct from global: tile t rows = tokens t*16 + i16
  half8v qf[3][2], kf[3][2];
#pragma unroll
  for (int t = 0; t < 3; ++t) {
    const _Float16* rp = token_row_ptr(t * 16 + i16, wy, wx, b, qkv0, qkv1, qkv2);
#pragma unroll
    for (int kc = 0; kc < 2; ++kc) {
      if (rp) {
        qf[t][kc] = *(const half8v*)(rp + h * HD + kc * 32 + q4 * 8);
        kf[t][kc] = *(const half8v*)(rp + 256 + h * HD + kc * 32 + q4 * 8);
      } else {
        qf[t][kc] = (half8v)(_Float16)0.f;
        kf[t][kc] = (half8v)(_Float16)0.f;
      }
    }
  }

  // --- QK^T: 9 tiles x 2 K-chunks
  floatx4 s[3][3] = {};
#pragma unroll
  for (int kc = 0; kc < 2; ++kc)
#pragma unroll
    for (int ti = 0; ti < 3; ++ti)
#pragma unroll
      for (int tj = 0; tj < 3; ++tj)
        s[ti][tj] = __builtin_amdgcn_mfma_f32_16x16x32_f16(qf[ti][kc], kf[tj][kc], s[ti][tj], 0, 0, 0);

  // --- pos bias + tile-pad mask (C layout: row = q4*4+r, col = i16)
#pragma unroll
  for (int ti = 0; ti < 3; ++ti)
#pragma unroll
    for (int tj = 0; tj < 3; ++tj)
#pragma unroll
      for (int r = 0; r < 4; ++r) {
        int i = ti * 16 + q4 * 4 + r;
        int j = tj * 16 + i16;
        if (j < NT) { if (i < NT) s[ti][tj][r] += pos[(h * NT + i) * NT + j]; }
        else s[ti][tj][r] = -INFINITY;
      }

  // --- softmax per row (3 regs + 16-lane shfl reduce), write P f16 to LDS
#pragma unroll
  for (int ti = 0; ti < 3; ++ti)
#pragma unroll
    for (int r = 0; r < 4; ++r) {
      float v0 = s[ti][0][r], v1 = s[ti][1][r], v2 = s[ti][2][r];
      float m = fmaxf(fmaxf(v0, v1), v2);
      m = fmaxf(m, __shfl_xor(m, 1));
      m = fmaxf(m, __shfl_xor(m, 2));
      m = fmaxf(m, __shfl_xor(m, 4));
      m = fmaxf(m, __shfl_xor(m, 8));
      float e0 = expf(v0 - m), e1 = expf(v1 - m), e2 = expf(v2 - m);
      float sum = e0 + e1 + e2;
      sum += __shfl_xor(sum, 1);
      sum += __shfl_xor(sum, 2);
      sum += __shfl_xor(sum, 4);
      sum += __shfl_xor(sum, 8);
      float inv = 1.f / sum;
      int i = ti * 16 + q4 * 4 + r;
      ps[h][i][ 0 + i16] = (_Float16)(e0 * inv);
      ps[h][i][16 + i16] = (_Float16)(e1 * inv);
      ps[h][i][32 + i16] = (_Float16)(e2 * inv);
    }

  // --- PV: A = P (3 m-tiles), B = V^T from vst (4 d-tiles); K = 32 + 16
  half8v vb0[4]; half4v vb1[4];
#pragma unroll
  for (int n = 0; n < 4; ++n) {
    vb0[n] = *(const half8v*)&vst[h][n * 16 + i16][q4 * 8];
    vb1[n] = *(const half4v*)&vst[h][n * 16 + i16][32 + q4 * 4];
  }
  const size_t obase = ((size_t)(b * NWIN + w) * NT) * C + h * HD;
#pragma unroll
  for (int mt = 0; mt < 3; ++mt) {
    half8v pa0 = *(const half8v*)&ps[h][mt * 16 + i16][q4 * 8];
    half4v pa1 = *(const half4v*)&ps[h][mt * 16 + i16][32 + q4 * 4];
    floatx4 o[4] = {};
#pragma unroll
    for (int n = 0; n < 4; ++n) {
      o[n] = __builtin_amdgcn_mfma_f32_16x16x32_f16(pa0, vb0[n], o[n], 0, 0, 0);
      o[n] = __builtin_amdgcn_mfma_f32_16x16x16f16(pa1, vb1[n], o[n], 0, 0, 0);
    }
#pragma unroll
    for (int r = 0; r < 4; ++r) {
      int i = mt * 16 + q4 * 4 + r;
      if (i < NT) {
#pragma unroll
        for (int n = 0; n < 4; ++n)
          O[obase + (size_t)i * C + n * 16 + i16] = (_Float16)o[n][r];
      }
    }
  }
}

// ---------------- proj GEMM (f16 MFMA) + bias, transposed store Yt[(b*C+c)*RPB + w*35+j] ----------------
__global__ __launch_bounds__(256) void proj_gemm(const _Float16* __restrict__ A,  // (Mg, 256) f16 row-major
                                                 const float* __restrict__ W,     // (256, 256) row-major
                                                 const float* __restrict__ bias,
                                                 float* __restrict__ Yt, int Mg) {
  __shared__ __align__(16) char smem[128 * 69 * 4];   // max(As+Bs = 15360, Cs = 35328)
  _Float16 (*As)[40] = (_Float16(*)[40])smem;
  _Float16 (*Bs)[40] = (_Float16(*)[40])(smem + 128 * 40 * 2);
  float    (*Cs)[69] = (float(*)[69])smem;

  const int tid  = threadIdx.x;
  const int m0   = blockIdx.x * 128;
  const int n0   = blockIdx.y * 64;
  const int w    = tid >> 6;
  const int lane = tid & 63;
  const int quad = lane >> 4;
  const int mn   = lane & 15;

  floatx4 acc[2][4] = {};
  for (int k0 = 0; k0 < C; k0 += 32) {
    // stage A (f16 row-major): straight half8 copies
#pragma unroll
    for (int u = 0; u < 2; ++u) {
      int e = u * 256 + tid;           // 512 units: 128 m x 4 k-octs
      int m = e >> 2, k8 = e & 3;
      int row = min(m0 + m, Mg - 1);
      half8v va = *(const half8v*)&A[(size_t)row * C + k0 + 8 * k8];
      *(half8v*)&As[m][8 * k8] = va;
    }
    // stage B (f32 -> f16)
    {
      int nq = tid & 15, kp = tid >> 4;
      const float* wp = W + (size_t)(k0 + 2 * kp) * C + n0 + 4 * nq;
      floatx4 va = *(const floatx4*)wp;
      floatx4 vb = *(const floatx4*)(wp + C);
#pragma unroll
      for (int i = 0; i < 4; ++i) *(unsigned*)&Bs[4 * nq + i][2 * kp] = pack2(va[i], vb[i]);
    }
    __syncthreads();
    half8v a0 = *(const half8v*)&As[w * 32 + mn][quad * 8];
    half8v a1 = *(const half8v*)&As[w * 32 + 16 + mn][quad * 8];
#pragma unroll
    for (int ni = 0; ni < 4; ++ni) {
      half8v bf = *(const half8v*)&Bs[ni * 16 + mn][quad * 8];
      acc[0][ni] = __builtin_amdgcn_mfma_f32_16x16x32_f16(a0, bf, acc[0][ni], 0, 0, 0);
      acc[1][ni] = __builtin_amdgcn_mfma_f32_16x16x32_f16(a1, bf, acc[1][ni], 0, 0, 0);
    }
    __syncthreads();   // also protects As/Bs before Cs aliasing overwrite
  }

  // epilogue: bias add into Cs, then transposed coalesced store
#pragma unroll
  for (int mi = 0; mi < 2; ++mi)
#pragma unroll
    for (int r = 0; r < 4; ++r)
#pragma unroll
      for (int ni = 0; ni < 4; ++ni)
        Cs[w * 32 + mi * 16 + quad * 4 + r][ni * 16 + mn] =
            acc[mi][ni][r] + bias[n0 + ni * 16 + mn];
  __syncthreads();
#pragma unroll
  for (int u = 0; u < 32; ++u) {
    int e = u * 256 + tid;            // 8192 elems: 128 m x 64 n
    int ml = e & 127, cl = e >> 7;
    int m = m0 + ml;
    if (m < Mg) {
      int bb = m / RPB;
      int r = m - bb * RPB;
      Yt[((size_t)bb * C + n0 + cl) * RPB + r] = Cs[ml][cl];
    }
  }
}

// ---------------- fold (gather form), group-local ----------------
__global__ __launch_bounds__(256) void fold_kernel(const float* __restrict__ Yt,
                                                   float* __restrict__ out,
                                                   int k_, int s_, int p_, int H_,
                                                   int toff, int total) {
  int idx = blockIdx.x * 256 + threadIdx.x;
  if (idx >= total) return;
  int x = idx % H_;
  int y = (idx / H_) % H_;
  int c = (idx / (H_ * H_)) % C;
  int b = idx / (C * H_ * H_);
  int py = y + p_, px = x + p_;
  int ay = py - k_ + 1;
  int wy_lo = ay <= 0 ? 0 : (ay + s_ - 1) / s_;
  int wy_hi = min(19, py / s_);
  int ax = px - k_ + 1;
  int wx_lo = ax <= 0 ? 0 : (ax + s_ - 1) / s_;
  int wx_hi = min(19, px / s_);
  const float* base = Yt + ((size_t)b * C + c) * RPB;
  float acc = 0.f;
  for (int wy = wy_lo; wy <= wy_hi; ++wy) {
    int tyy = py - wy * s_;
    for (int wx = wx_lo; wx <= wx_hi; ++wx) {
      int txx = px - wx * s_;
      acc += base[(wy * 20 + wx) * NT + toff + tyy * k_ + txx];
    }
  }
  out[idx] = acc;
}

} // namespace

extern "C" void kernel_launch(void* const* d_in, const int* in_sizes, int n_in,
                              void* d_out, int out_size, void* d_ws, size_t ws_size,
                              hipStream_t stream) {
  const float* x0    = (const float*)d_in[0];
  const float* x1    = (const float*)d_in[1];
  const float* x2    = (const float*)d_in[2];
  const float* wq0   = (const float*)d_in[3];
  const float* wq1   = (const float*)d_in[4];
  const float* wq2   = (const float*)d_in[5];
  const float* wproj = (const float*)d_in[6];
  const float* bproj = (const float*)d_in[7];
  const float* rpb   = (const float*)d_in[8];
  const float* ab    = (const float*)d_in[9];
  float* out = (float*)d_out;

  // pick largest batch-group size g in {8,4,2,1} that fits ws_size
  int g = 8;
  while (g > 1 && POS_B + (size_t)g * PB_B > ws_size) g >>= 1;

  char* ws = (char*)d_ws;
  float*    posb  = (float*)ws;
  _Float16* qkv0g = (_Float16*)(ws + POS_B);
  _Float16* qkv1g = qkv0g + (size_t)g * 6400 * QKVN;
  _Float16* qkv2g = qkv1g + (size_t)g * 1600 * QKVN;
  _Float16* oatt  = qkv2g + (size_t)g *  400 * QKVN;
  float*    yt    = (float*)(ws + POS_B + (size_t)g * (QKV_B + OATT_B));

  pos_kernel<<<(NH * NT * NT + 255) / 256, 256, 0, stream>>>(rpb, ab, posb);

  const size_t off1 = (size_t)B * C * 6400;
  const size_t off2 = off1 + (size_t)B * C * 1600;

  for (int b0 = 0; b0 < B; b0 += g) {
    const float* x0g = x0 + (size_t)b0 * C * 6400;
    const float* x1g = x1 + (size_t)b0 * C * 1600;
    const float* x2g = x2 + (size_t)b0 * C * 400;

    qkv_gemm<<<dim3((g * 6400 + 127) / 128, QKVN / 128), 256, 0, stream>>>(x0g, wq0, qkv0g, 6400, g * 6400, 512);
    qkv_gemm<<<dim3((g * 1600 + 127) / 128, QKVN / 128), 256, 0, stream>>>(x1g, wq1, qkv1g, 1600, g * 1600, 512);
    qkv_gemm<<<dim3((g *  400 + 127) / 128, QKVN / 128), 256, 0, stream>>>(x2g, wq2, qkv2g,  400, g *  400, 512);

    attn_kernel<<<g * NWIN, 256, 0, stream>>>(qkv0g, qkv1g, qkv2g, posb, oatt);

    proj_gemm<<<dim3((g * RPB + 127) / 128, C / 64), 256, 0, stream>>>(oatt, wproj, bproj, yt, g * RPB);

    const int tot0 = g * C * 6400;
    const int tot1 = g * C * 1600;
    const int tot2 = g * C * 400;
    fold_kernel<<<(tot0 + 255) / 256, 256, 0, stream>>>(yt, out + (size_t)b0 * C * 6400,        5, 4, 2, 80, 0,  tot0);
    fold_kernel<<<(tot1 + 255) / 256, 256, 0, stream>>>(yt, out + off1 + (size_t)b0 * C * 1600, 3, 2, 1, 40, 25, tot1);
    fold_kernel<<<(tot2 + 255) / 256, 256, 0, stream>>>(yt, out + off2 + (size_t)b0 * C * 400,  1, 1, 0, 20, 34, tot2);
  }
}

// Round 2
// 582.109 us; speedup vs baseline: 1.2736x; 1.2057x over previous
//
#include <hip/hip_runtime.h>
#include <math.h>

namespace {

typedef _Float16 half8v __attribute__((ext_vector_type(8)));
typedef _Float16 half4v __attribute__((ext_vector_type(4)));
typedef float    floatx4 __attribute__((ext_vector_type(4)));

constexpr int B   = 8;
constexpr int C   = 256;
constexpr int NH  = 4;
constexpr int HD  = 64;
constexpr int NWIN = 400;   // 20x20 windows per level
constexpr int NT  = 35;     // 25 + 9 + 1 tokens per window
constexpr int QKVN = 768;
constexpr int RPB = NWIN * NT;  // 14,000 token-rows per batch

// per-batch byte counts for workspace
constexpr size_t QKV_B  = (size_t)8400 * QKVN * 2;   // 12,902,400  (f16)
constexpr size_t OATT_B = (size_t)RPB * C * 2;       //  7,168,000  (f16)
constexpr size_t YT_B   = (size_t)RPB * C * 4;       // 14,336,000  (f32)
constexpr size_t PB_B   = QKV_B + OATT_B + YT_B;     // 34,406,400
constexpr size_t POS_B  = 19712;                     // 4900 f32, padded

__device__ inline unsigned pack2(float a, float b) {
  union { _Float16 h[2]; unsigned u; } x;
  x.h[0] = (_Float16)a; x.h[1] = (_Float16)b;
  return x.u;
}

// ---------------- pos table ----------------
__device__ inline void token_coord(int j, double& cy, double& cx) {
  if (j < 25)      { int ty = j / 5,  tx = j % 5;  cy = (double)(ty - 2); cx = (double)(tx - 2); }
  else if (j < 34) { int t = j - 25; int ty = t / 3, tx = t % 3;
                     cy = (double)(ty - 1) * (5.0 / 3.0); cx = (double)(tx - 1) * (5.0 / 3.0); }
  else             { cy = 0.0; cx = 0.0; }
}

__global__ void pos_kernel(const float* __restrict__ rpb, const float* __restrict__ ab,
                           float* __restrict__ pos) {
  int p = blockIdx.x * blockDim.x + threadIdx.x;
  if (p >= NH * NT * NT) return;
  int j = p % NT, i = (p / NT) % NT, h = p / (NT * NT);
  double cyi, cxi, cyj, cxj;
  token_coord(i, cyi, cxi);
  token_coord(j, cyj, cxj);
  float fidx = (float)(((cyi - cyj) + 4.0) * 9.0 + ((cxi - cxj) + 4.0));
  int fl = min(max((int)floorf(fidx), 0), 80);
  int ce = min(max((int)ceilf(fidx), 0), 80);
  float w = fidx - (float)fl;
  float pv = (1.0f - w) * rpb[fl * NH + h] + w * rpb[ce * NH + h];
  int li = (i < 25) ? 0 : ((i < 34) ? 1 : 2);
  pos[p] = pv + ab[li * NH + h];
}

// ---------------- QKV GEMM (f16 MFMA, 128x128 tile): Y[m, 768](f16) = X^T @ W ----------------
// Staging: each lane owns one LDS row-segment (8 contiguous k), reads 8 k-strided f32 from
// global (coalesced across lanes: 64x4B = 256B/instr), converts in-register, writes one
// ds_write_b128. Row-segment writes hit all 32 banks evenly (row stride 80B) -> no conflicts.
// Epilogue: L2-normalize each output row per 64-col head section when n0 < normN (q,k).
__global__ __launch_bounds__(256) void qkv_gemm(const float* __restrict__ X,
                                                const float* __restrict__ W,
                                                _Float16* __restrict__ Y,
                                                int HW, int Mg, int normN) {
  __shared__ _Float16 As[128][40];   // row 80B, 16B-aligned frag reads
  __shared__ _Float16 Bs[128][40];
  const int tid  = threadIdx.x;
  const int m0   = blockIdx.x * 128;
  const int n0   = blockIdx.y * 128;
  const int w    = tid >> 6;
  const int lane = tid & 63;
  const int quad = lane >> 4;
  const int mn   = lane & 15;

  floatx4 acc[2][8] = {};
  for (int k0 = 0; k0 < C; k0 += 32) {
    // chunk c in 0..7: (half = c>>2) x (k-oct = c&3); wave w stages chunks {2w, 2w+1}
    float av[2][8], bv[2][8];
    int rl[2];
#pragma unroll
    for (int u = 0; u < 2; ++u) {
      int c = w * 2 + u;
      int ko = c & 3;
      rl[u] = (c >> 2) * 64 + lane;
      // A: X is [C][HW] per batch; row gm of A = pixel, col = channel
      int gm = min(m0 + rl[u], Mg - 1);
      int bb = gm / HW, pix = gm - bb * HW;
      const float* xp = X + ((size_t)bb * C + k0 + ko * 8) * HW + pix;
#pragma unroll
      for (int j = 0; j < 8; ++j) av[u][j] = xp[(size_t)j * HW];
      // B: W is [K][QKVN] row-major
      const float* wp = W + (size_t)(k0 + ko * 8) * QKVN + n0 + rl[u];
#pragma unroll
      for (int j = 0; j < 8; ++j) bv[u][j] = wp[(size_t)j * QKVN];
    }
#pragma unroll
    for (int u = 0; u < 2; ++u) {
      int ko = (w * 2 + u) & 3;
      half8v ha, hb;
#pragma unroll
      for (int j = 0; j < 8; ++j) { ha[j] = (_Float16)av[u][j]; hb[j] = (_Float16)bv[u][j]; }
      *(half8v*)&As[rl[u]][ko * 8] = ha;
      *(half8v*)&Bs[rl[u]][ko * 8] = hb;
    }
    __syncthreads();
    half8v a0 = *(const half8v*)&As[w * 32 + mn][quad * 8];
    half8v a1 = *(const half8v*)&As[w * 32 + 16 + mn][quad * 8];
#pragma unroll
    for (int ni = 0; ni < 8; ++ni) {
      half8v bf = *(const half8v*)&Bs[ni * 16 + mn][quad * 8];
      acc[0][ni] = __builtin_amdgcn_mfma_f32_16x16x32_f16(a0, bf, acc[0][ni], 0, 0, 0);
      acc[1][ni] = __builtin_amdgcn_mfma_f32_16x16x32_f16(a1, bf, acc[1][ni], 0, 0, 0);
    }
    __syncthreads();
  }

  // epilogue: per-row L2 norm per 64-col head section (two sections per 128-tile)
  const bool do_norm = (n0 < normN);
#pragma unroll
  for (int mi = 0; mi < 2; ++mi) {
#pragma unroll
    for (int r = 0; r < 4; ++r) {
      float s0 = 0.f, s1 = 0.f;
#pragma unroll
      for (int ni = 0; ni < 4; ++ni) { float vv = acc[mi][ni][r]; s0 += vv * vv; }
#pragma unroll
      for (int ni = 4; ni < 8; ++ni) { float vv = acc[mi][ni][r]; s1 += vv * vv; }
      s0 += __shfl_xor(s0, 1); s1 += __shfl_xor(s1, 1);
      s0 += __shfl_xor(s0, 2); s1 += __shfl_xor(s1, 2);
      s0 += __shfl_xor(s0, 4); s1 += __shfl_xor(s1, 4);
      s0 += __shfl_xor(s0, 8); s1 += __shfl_xor(s1, 8);
      float sc0 = do_norm ? (1.f / fmaxf(sqrtf(s0), 1e-12f)) : 1.f;
      float sc1 = do_norm ? (1.f / fmaxf(sqrtf(s1), 1e-12f)) : 1.f;
      int row = m0 + w * 32 + mi * 16 + quad * 4 + r;
      if (row < Mg) {
#pragma unroll
        for (int ni = 0; ni < 8; ++ni)
          Y[(size_t)row * QKVN + n0 + ni * 16 + mn] =
              (_Float16)(acc[mi][ni][r] * (ni < 4 ? sc0 : sc1));
      }
    }
  }
}

// ---------------- attention: MFMA version. Block = (b_local, window); wave = head. ----------------
__device__ inline const _Float16* token_row_ptr(int j, int wy, int wx, int b,
                                                const _Float16* q0, const _Float16* q1,
                                                const _Float16* q2) {
  if (j >= NT) return nullptr;
  int k_, s_, p_, Hl, t; const _Float16* base;
  if (j < 25)      { k_ = 5; s_ = 4; p_ = 2; Hl = 80; t = j;      base = q0; }
  else if (j < 34) { k_ = 3; s_ = 2; p_ = 1; Hl = 40; t = j - 25; base = q1; }
  else             { k_ = 1; s_ = 1; p_ = 0; Hl = 20; t = 0;      base = q2; }
  int ty = t / k_, tx = t % k_;
  int y = wy * s_ + ty - p_;
  int x = wx * s_ + tx - p_;
  if ((unsigned)y >= (unsigned)Hl || (unsigned)x >= (unsigned)Hl) return nullptr;
  return base + ((size_t)b * Hl * Hl + (size_t)y * Hl + x) * QKVN;
}

__global__ __launch_bounds__(256) void attn_kernel(const _Float16* __restrict__ qkv0,
                                                   const _Float16* __restrict__ qkv1,
                                                   const _Float16* __restrict__ qkv2,
                                                   const float* __restrict__ pos,
                                                   _Float16* __restrict__ O) {
  const int blk = blockIdx.x;               // b*NWIN + w
  const int w   = blk % NWIN;
  const int b   = blk / NWIN;
  const int wy = w / 20, wx = w % 20;
  const int tid  = threadIdx.x;
  const int h    = tid >> 6;                // wave = head
  const int lane = tid & 63;
  const int i16  = lane & 15;
  const int q4   = lane >> 4;

  // rows padded to 56 halfs (112 B): 16B-aligned frag reads, 2-way bank alias (free)
  __shared__ _Float16 vst[NH][64][56];      // V transposed: [d][j], j zero-padded to 48
  __shared__ _Float16 ps [NH][48][56];      // P (f16) [i][j]

  // --- stage V transposed (lane = d); j >= NT or invalid token -> 0
  for (int j = 0; j < 48; ++j) {
    _Float16 val = (_Float16)0.f;
    if (j < NT) {
      const _Float16* rp = token_row_ptr(j, wy, wx, b, qkv0, qkv1, qkv2);
      if (rp) val = rp[512 + h * HD + lane];
    }
    vst[h][lane][j] = val;
  }

  // --- Q/K fragments direct from global: tile t rows = tokens t*16 + i16
  half8v qf[3][2], kf[3][2];
#pragma unroll
  for (int t = 0; t < 3; ++t) {
    const _Float16* rp = token_row_ptr(t * 16 + i16, wy, wx, b, qkv0, qkv1, qkv2);
#pragma unroll
    for (int kc = 0; kc < 2; ++kc) {
      if (rp) {
        qf[t][kc] = *(const half8v*)(rp + h * HD + kc * 32 + q4 * 8);
        kf[t][kc] = *(const half8v*)(rp + 256 + h * HD + kc * 32 + q4 * 8);
      } else {
        qf[t][kc] = (half8v)(_Float16)0.f;
        kf[t][kc] = (half8v)(_Float16)0.f;
      }
    }
  }

  // --- QK^T: 9 tiles x 2 K-chunks
  floatx4 s[3][3] = {};
#pragma unroll
  for (int kc = 0; kc < 2; ++kc)
#pragma unroll
    for (int ti = 0; ti < 3; ++ti)
#pragma unroll
      for (int tj = 0; tj < 3; ++tj)
        s[ti][tj] = __builtin_amdgcn_mfma_f32_16x16x32_f16(qf[ti][kc], kf[tj][kc], s[ti][tj], 0, 0, 0);

  // --- pos bias + tile-pad mask (C layout: row = q4*4+r, col = i16)
#pragma unroll
  for (int ti = 0; ti < 3; ++ti)
#pragma unroll
    for (int tj = 0; tj < 3; ++tj)
#pragma unroll
      for (int r = 0; r < 4; ++r) {
        int i = ti * 16 + q4 * 4 + r;
        int j = tj * 16 + i16;
        if (j < NT) { if (i < NT) s[ti][tj][r] += pos[(h * NT + i) * NT + j]; }
        else s[ti][tj][r] = -INFINITY;
      }

  // --- softmax per row (3 regs + 16-lane shfl reduce), write P f16 to LDS
#pragma unroll
  for (int ti = 0; ti < 3; ++ti)
#pragma unroll
    for (int r = 0; r < 4; ++r) {
      float v0 = s[ti][0][r], v1 = s[ti][1][r], v2 = s[ti][2][r];
      float m = fmaxf(fmaxf(v0, v1), v2);
      m = fmaxf(m, __shfl_xor(m, 1));
      m = fmaxf(m, __shfl_xor(m, 2));
      m = fmaxf(m, __shfl_xor(m, 4));
      m = fmaxf(m, __shfl_xor(m, 8));
      float e0 = expf(v0 - m), e1 = expf(v1 - m), e2 = expf(v2 - m);
      float sum = e0 + e1 + e2;
      sum += __shfl_xor(sum, 1);
      sum += __shfl_xor(sum, 2);
      sum += __shfl_xor(sum, 4);
      sum += __shfl_xor(sum, 8);
      float inv = 1.f / sum;
      int i = ti * 16 + q4 * 4 + r;
      ps[h][i][ 0 + i16] = (_Float16)(e0 * inv);
      ps[h][i][16 + i16] = (_Float16)(e1 * inv);
      ps[h][i][32 + i16] = (_Float16)(e2 * inv);
    }

  // --- PV: A = P (3 m-tiles), B = V^T from vst (4 d-tiles); K = 32 + 16
  half8v vb0[4]; half4v vb1[4];
#pragma unroll
  for (int n = 0; n < 4; ++n) {
    vb0[n] = *(const half8v*)&vst[h][n * 16 + i16][q4 * 8];
    vb1[n] = *(const half4v*)&vst[h][n * 16 + i16][32 + q4 * 4];
  }
  const size_t obase = ((size_t)(b * NWIN + w) * NT) * C + h * HD;
#pragma unroll
  for (int mt = 0; mt < 3; ++mt) {
    half8v pa0 = *(const half8v*)&ps[h][mt * 16 + i16][q4 * 8];
    half4v pa1 = *(const half4v*)&ps[h][mt * 16 + i16][32 + q4 * 4];
    floatx4 o[4] = {};
#pragma unroll
    for (int n = 0; n < 4; ++n) {
      o[n] = __builtin_amdgcn_mfma_f32_16x16x32_f16(pa0, vb0[n], o[n], 0, 0, 0);
      o[n] = __builtin_amdgcn_mfma_f32_16x16x16f16(pa1, vb1[n], o[n], 0, 0, 0);
    }
#pragma unroll
    for (int r = 0; r < 4; ++r) {
      int i = mt * 16 + q4 * 4 + r;
      if (i < NT) {
#pragma unroll
        for (int n = 0; n < 4; ++n)
          O[obase + (size_t)i * C + n * 16 + i16] = (_Float16)o[n][r];
      }
    }
  }
}

// ---------------- proj GEMM (f16 MFMA) + bias, transposed store Yt[(b*C+c)*RPB + w*35+j] ----------------
__global__ __launch_bounds__(256) void proj_gemm(const _Float16* __restrict__ A,  // (Mg, 256) f16 row-major
                                                 const float* __restrict__ W,     // (256, 256) row-major
                                                 const float* __restrict__ bias,
                                                 float* __restrict__ Yt, int Mg) {
  __shared__ __align__(16) char smem[128 * 69 * 4];   // max(As+Bs = 15360, Cs = 35328)
  _Float16 (*As)[40] = (_Float16(*)[40])smem;
  _Float16 (*Bs)[40] = (_Float16(*)[40])(smem + 128 * 40 * 2);
  float    (*Cs)[69] = (float(*)[69])smem;

  const int tid  = threadIdx.x;
  const int m0   = blockIdx.x * 128;
  const int n0   = blockIdx.y * 64;
  const int w    = tid >> 6;
  const int lane = tid & 63;
  const int quad = lane >> 4;
  const int mn   = lane & 15;

  floatx4 acc[2][4] = {};
  for (int k0 = 0; k0 < C; k0 += 32) {
    // stage A (f16 row-major): straight half8 copies
#pragma unroll
    for (int u = 0; u < 2; ++u) {
      int e = u * 256 + tid;           // 512 units: 128 m x 4 k-octs
      int m = e >> 2, k8 = e & 3;
      int row = min(m0 + m, Mg - 1);
      half8v va = *(const half8v*)&A[(size_t)row * C + k0 + 8 * k8];
      *(half8v*)&As[m][8 * k8] = va;
    }
    // stage B: wave w stages k-oct w for all 64 n; lane owns row n=lane, 8 k-strided reads,
    // one contiguous half8 (b128) write -> conflict-free
    {
      const float* wp = W + (size_t)(k0 + w * 8) * C + n0 + lane;
      float wv[8];
#pragma unroll
      for (int j = 0; j < 8; ++j) wv[j] = wp[(size_t)j * C];
      half8v hv;
#pragma unroll
      for (int j = 0; j < 8; ++j) hv[j] = (_Float16)wv[j];
      *(half8v*)&Bs[lane][w * 8] = hv;
    }
    __syncthreads();
    half8v a0 = *(const half8v*)&As[w * 32 + mn][quad * 8];
    half8v a1 = *(const half8v*)&As[w * 32 + 16 + mn][quad * 8];
#pragma unroll
    for (int ni = 0; ni < 4; ++ni) {
      half8v bf = *(const half8v*)&Bs[ni * 16 + mn][quad * 8];
      acc[0][ni] = __builtin_amdgcn_mfma_f32_16x16x32_f16(a0, bf, acc[0][ni], 0, 0, 0);
      acc[1][ni] = __builtin_amdgcn_mfma_f32_16x16x32_f16(a1, bf, acc[1][ni], 0, 0, 0);
    }
    __syncthreads();   // also protects As/Bs before Cs aliasing overwrite
  }

  // epilogue: bias add into Cs, then transposed coalesced store
#pragma unroll
  for (int mi = 0; mi < 2; ++mi)
#pragma unroll
    for (int r = 0; r < 4; ++r)
#pragma unroll
      for (int ni = 0; ni < 4; ++ni)
        Cs[w * 32 + mi * 16 + quad * 4 + r][ni * 16 + mn] =
            acc[mi][ni][r] + bias[n0 + ni * 16 + mn];
  __syncthreads();
#pragma unroll
  for (int u = 0; u < 32; ++u) {
    int e = u * 256 + tid;            // 8192 elems: 128 m x 64 n
    int ml = e & 127, cl = e >> 7;
    int m = m0 + ml;
    if (m < Mg) {
      int bb = m / RPB;
      int r = m - bb * RPB;
      Yt[((size_t)bb * C + n0 + cl) * RPB + r] = Cs[ml][cl];
    }
  }
}

// ---------------- fold (gather form), group-local ----------------
__global__ __launch_bounds__(256) void fold_kernel(const float* __restrict__ Yt,
                                                   float* __restrict__ out,
                                                   int k_, int s_, int p_, int H_,
                                                   int toff, int total) {
  int idx = blockIdx.x * 256 + threadIdx.x;
  if (idx >= total) return;
  int x = idx % H_;
  int y = (idx / H_) % H_;
  int c = (idx / (H_ * H_)) % C;
  int b = idx / (C * H_ * H_);
  int py = y + p_, px = x + p_;
  int ay = py - k_ + 1;
  int wy_lo = ay <= 0 ? 0 : (ay + s_ - 1) / s_;
  int wy_hi = min(19, py / s_);
  int ax = px - k_ + 1;
  int wx_lo = ax <= 0 ? 0 : (ax + s_ - 1) / s_;
  int wx_hi = min(19, px / s_);
  const float* base = Yt + ((size_t)b * C + c) * RPB;
  float acc = 0.f;
  for (int wy = wy_lo; wy <= wy_hi; ++wy) {
    int tyy = py - wy * s_;
    for (int wx = wx_lo; wx <= wx_hi; ++wx) {
      int txx = px - wx * s_;
      acc += base[(wy * 20 + wx) * NT + toff + tyy * k_ + txx];
    }
  }
  out[idx] = acc;
}

} // namespace

extern "C" void kernel_launch(void* const* d_in, const int* in_sizes, int n_in,
                              void* d_out, int out_size, void* d_ws, size_t ws_size,
                              hipStream_t stream) {
  const float* x0    = (const float*)d_in[0];
  const float* x1    = (const float*)d_in[1];
  const float* x2    = (const float*)d_in[2];
  const float* wq0   = (const float*)d_in[3];
  const float* wq1   = (const float*)d_in[4];
  const float* wq2   = (const float*)d_in[5];
  const float* wproj = (const float*)d_in[6];
  const float* bproj = (const float*)d_in[7];
  const float* rpb   = (const float*)d_in[8];
  const float* ab    = (const float*)d_in[9];
  float* out = (float*)d_out;

  // pick largest batch-group size g in {8,4,2,1} that fits ws_size
  int g = 8;
  while (g > 1 && POS_B + (size_t)g * PB_B > ws_size) g >>= 1;

  char* ws = (char*)d_ws;
  float*    posb  = (float*)ws;
  _Float16* qkv0g = (_Float16*)(ws + POS_B);
  _Float16* qkv1g = qkv0g + (size_t)g * 6400 * QKVN;
  _Float16* qkv2g = qkv1g + (size_t)g * 1600 * QKVN;
  _Float16* oatt  = qkv2g + (size_t)g *  400 * QKVN;
  float*    yt    = (float*)(ws + POS_B + (size_t)g * (QKV_B + OATT_B));

  pos_kernel<<<(NH * NT * NT + 255) / 256, 256, 0, stream>>>(rpb, ab, posb);

  const size_t off1 = (size_t)B * C * 6400;
  const size_t off2 = off1 + (size_t)B * C * 1600;

  for (int b0 = 0; b0 < B; b0 += g) {
    const float* x0g = x0 + (size_t)b0 * C * 6400;
    const float* x1g = x1 + (size_t)b0 * C * 1600;
    const float* x2g = x2 + (size_t)b0 * C * 400;

    qkv_gemm<<<dim3((g * 6400 + 127) / 128, QKVN / 128), 256, 0, stream>>>(x0g, wq0, qkv0g, 6400, g * 6400, 512);
    qkv_gemm<<<dim3((g * 1600 + 127) / 128, QKVN / 128), 256, 0, stream>>>(x1g, wq1, qkv1g, 1600, g * 1600, 512);
    qkv_gemm<<<dim3((g *  400 + 127) / 128, QKVN / 128), 256, 0, stream>>>(x2g, wq2, qkv2g,  400, g *  400, 512);

    attn_kernel<<<g * NWIN, 256, 0, stream>>>(qkv0g, qkv1g, qkv2g, posb, oatt);

    proj_gemm<<<dim3((g * RPB + 127) / 128, C / 64), 256, 0, stream>>>(oatt, wproj, bproj, yt, g * RPB);

    const int tot0 = g * C * 6400;
    const int tot1 = g * C * 1600;
    const int tot2 = g * C * 400;
    fold_kernel<<<(tot0 + 255) / 256, 256, 0, stream>>>(yt, out + (size_t)b0 * C * 6400,        5, 4, 2, 80, 0,  tot0);
    fold_kernel<<<(tot1 + 255) / 256, 256, 0, stream>>>(yt, out + off1 + (size_t)b0 * C * 1600, 3, 2, 1, 40, 25, tot1);
    fold_kernel<<<(tot2 + 255) / 256, 256, 0, stream>>>(yt, out + off2 + (size_t)b0 * C * 400,  1, 1, 0, 20, 34, tot2);
  }
}

// Round 3
// 515.868 us; speedup vs baseline: 1.4372x; 1.1284x over previous
//
#include <hip/hip_runtime.h>
#include <math.h>

namespace {

typedef _Float16 half8v __attribute__((ext_vector_type(8)));
typedef _Float16 half4v __attribute__((ext_vector_type(4)));
typedef float    floatx4 __attribute__((ext_vector_type(4)));

constexpr int B   = 8;
constexpr int C   = 256;
constexpr int NH  = 4;
constexpr int HD  = 64;
constexpr int NWIN = 400;   // 20x20 windows per level
constexpr int NT  = 35;     // 25 + 9 + 1 tokens per window
constexpr int QKVN = 768;
constexpr int RPB = NWIN * NT;  // 14,000 token-rows per batch

// per-batch byte counts for workspace
constexpr size_t QKV_B  = (size_t)8400 * QKVN * 2;   // 12,902,400  (f16)
constexpr size_t OATT_B = (size_t)RPB * C * 2;       //  7,168,000  (f16)
constexpr size_t YT_B   = (size_t)RPB * C * 4;       // 14,336,000  (f32)
constexpr size_t PB_B   = QKV_B + OATT_B + YT_B;     // 34,406,400
constexpr size_t POS_B  = 19712;                     // 4900 f32, padded

__device__ inline unsigned pack2(float a, float b) {
  union { _Float16 h[2]; unsigned u; } x;
  x.h[0] = (_Float16)a; x.h[1] = (_Float16)b;
  return x.u;
}

// ---------------- pos table ----------------
__device__ inline void token_coord(int j, double& cy, double& cx) {
  if (j < 25)      { int ty = j / 5,  tx = j % 5;  cy = (double)(ty - 2); cx = (double)(tx - 2); }
  else if (j < 34) { int t = j - 25; int ty = t / 3, tx = t % 3;
                     cy = (double)(ty - 1) * (5.0 / 3.0); cx = (double)(tx - 1) * (5.0 / 3.0); }
  else             { cy = 0.0; cx = 0.0; }
}

__global__ void pos_kernel(const float* __restrict__ rpb, const float* __restrict__ ab,
                           float* __restrict__ pos) {
  int p = blockIdx.x * blockDim.x + threadIdx.x;
  if (p >= NH * NT * NT) return;
  int j = p % NT, i = (p / NT) % NT, h = p / (NT * NT);
  double cyi, cxi, cyj, cxj;
  token_coord(i, cyi, cxi);
  token_coord(j, cyj, cxj);
  float fidx = (float)(((cyi - cyj) + 4.0) * 9.0 + ((cxi - cxj) + 4.0));
  int fl = min(max((int)floorf(fidx), 0), 80);
  int ce = min(max((int)ceilf(fidx), 0), 80);
  float w = fidx - (float)fl;
  float pv = (1.0f - w) * rpb[fl * NH + h] + w * rpb[ce * NH + h];
  int li = (i < 25) ? 0 : ((i < 34) ? 1 : 2);
  pos[p] = pv + ab[li * NH + h];
}

// ---------------- QKV GEMM (f16 MFMA, 128x128 tile): Y[m, 768](f16) = X^T @ W ----------------
__global__ __launch_bounds__(256) void qkv_gemm(const float* __restrict__ X,
                                                const float* __restrict__ W,
                                                _Float16* __restrict__ Y,
                                                int HW, int Mg, int normN) {
  __shared__ _Float16 As[128][40];   // row 80B, 16B-aligned frag reads
  __shared__ _Float16 Bs[128][40];
  const int tid  = threadIdx.x;
  const int m0   = blockIdx.x * 128;
  const int n0   = blockIdx.y * 128;
  const int w    = tid >> 6;
  const int lane = tid & 63;
  const int quad = lane >> 4;
  const int mn   = lane & 15;

  floatx4 acc[2][8] = {};
  for (int k0 = 0; k0 < C; k0 += 32) {
    // chunk c in 0..7: (half = c>>2) x (k-oct = c&3); wave w stages chunks {2w, 2w+1}
    float av[2][8], bv[2][8];
    int rl[2];
#pragma unroll
    for (int u = 0; u < 2; ++u) {
      int c = w * 2 + u;
      int ko = c & 3;
      rl[u] = (c >> 2) * 64 + lane;
      // A: X is [C][HW] per batch; row gm of A = pixel, col = channel
      int gm = min(m0 + rl[u], Mg - 1);
      int bb = gm / HW, pix = gm - bb * HW;
      const float* xp = X + ((size_t)bb * C + k0 + ko * 8) * HW + pix;
#pragma unroll
      for (int j = 0; j < 8; ++j) av[u][j] = xp[(size_t)j * HW];
      // B: W is [K][QKVN] row-major
      const float* wp = W + (size_t)(k0 + ko * 8) * QKVN + n0 + rl[u];
#pragma unroll
      for (int j = 0; j < 8; ++j) bv[u][j] = wp[(size_t)j * QKVN];
    }
#pragma unroll
    for (int u = 0; u < 2; ++u) {
      int ko = (w * 2 + u) & 3;
      half8v ha, hb;
#pragma unroll
      for (int j = 0; j < 8; ++j) { ha[j] = (_Float16)av[u][j]; hb[j] = (_Float16)bv[u][j]; }
      *(half8v*)&As[rl[u]][ko * 8] = ha;
      *(half8v*)&Bs[rl[u]][ko * 8] = hb;
    }
    __syncthreads();
    half8v a0 = *(const half8v*)&As[w * 32 + mn][quad * 8];
    half8v a1 = *(const half8v*)&As[w * 32 + 16 + mn][quad * 8];
#pragma unroll
    for (int ni = 0; ni < 8; ++ni) {
      half8v bf = *(const half8v*)&Bs[ni * 16 + mn][quad * 8];
      acc[0][ni] = __builtin_amdgcn_mfma_f32_16x16x32_f16(a0, bf, acc[0][ni], 0, 0, 0);
      acc[1][ni] = __builtin_amdgcn_mfma_f32_16x16x32_f16(a1, bf, acc[1][ni], 0, 0, 0);
    }
    __syncthreads();
  }

  // epilogue: per-row L2 norm per 64-col head section (two sections per 128-tile)
  const bool do_norm = (n0 < normN);
#pragma unroll
  for (int mi = 0; mi < 2; ++mi) {
#pragma unroll
    for (int r = 0; r < 4; ++r) {
      float s0 = 0.f, s1 = 0.f;
#pragma unroll
      for (int ni = 0; ni < 4; ++ni) { float vv = acc[mi][ni][r]; s0 += vv * vv; }
#pragma unroll
      for (int ni = 4; ni < 8; ++ni) { float vv = acc[mi][ni][r]; s1 += vv * vv; }
      s0 += __shfl_xor(s0, 1); s1 += __shfl_xor(s1, 1);
      s0 += __shfl_xor(s0, 2); s1 += __shfl_xor(s1, 2);
      s0 += __shfl_xor(s0, 4); s1 += __shfl_xor(s1, 4);
      s0 += __shfl_xor(s0, 8); s1 += __shfl_xor(s1, 8);
      float sc0 = do_norm ? (1.f / fmaxf(sqrtf(s0), 1e-12f)) : 1.f;
      float sc1 = do_norm ? (1.f / fmaxf(sqrtf(s1), 1e-12f)) : 1.f;
      int row = m0 + w * 32 + mi * 16 + quad * 4 + r;
      if (row < Mg) {
#pragma unroll
        for (int ni = 0; ni < 8; ++ni)
          Y[(size_t)row * QKVN + n0 + ni * 16 + mn] =
              (_Float16)(acc[mi][ni][r] * (ni < 4 ? sc0 : sc1));
      }
    }
  }
}

// ---------------- attention: MFMA version. Block = (b_local, window); wave = head. ----------------
// V staged cooperatively by all 256 threads, ROW-major [48][258] (parallel coalesced loads,
// conflict-free b128 writes); B-frags rebuilt via scalar ds_read_u16 (stride 258 halfs = 129
// words == 1 mod 32 -> zero bank conflicts). P staged per-wave at row stride 60 halfs (4-row
// step == 24 mod 32 -> writes partition banks perfectly). Q/K frags direct from global.
__device__ inline const _Float16* token_row_ptr(int j, int wy, int wx, int b,
                                                const _Float16* q0, const _Float16* q1,
                                                const _Float16* q2) {
  if (j >= NT) return nullptr;
  int k_, s_, p_, Hl, t; const _Float16* base;
  if (j < 25)      { k_ = 5; s_ = 4; p_ = 2; Hl = 80; t = j;      base = q0; }
  else if (j < 34) { k_ = 3; s_ = 2; p_ = 1; Hl = 40; t = j - 25; base = q1; }
  else             { k_ = 1; s_ = 1; p_ = 0; Hl = 20; t = 0;      base = q2; }
  int ty = t / k_, tx = t % k_;
  int y = wy * s_ + ty - p_;
  int x = wx * s_ + tx - p_;
  if ((unsigned)y >= (unsigned)Hl || (unsigned)x >= (unsigned)Hl) return nullptr;
  return base + ((size_t)b * Hl * Hl + (size_t)y * Hl + x) * QKVN;
}

__global__ __launch_bounds__(256) void attn_kernel(const _Float16* __restrict__ qkv0,
                                                   const _Float16* __restrict__ qkv1,
                                                   const _Float16* __restrict__ qkv2,
                                                   const float* __restrict__ pos,
                                                   _Float16* __restrict__ O) {
  const int blk = blockIdx.x;               // b*NWIN + w
  const int w   = blk % NWIN;
  const int b   = blk / NWIN;
  const int wy = w / 20, wx = w % 20;
  const int tid  = threadIdx.x;
  const int h    = tid >> 6;                // wave = head
  const int lane = tid & 63;
  const int i16  = lane & 15;
  const int q4   = lane >> 4;

  __shared__ _Float16 vrows[48][258];       // V row-major, all heads; rows 35..47 zero
  __shared__ _Float16 ps[NH][48][60];       // P (f16) [i][k], wave-private per head

  // --- cooperative V staging: 1536 half8-chunks = 48 rows x 32 chunks over 256 threads
#pragma unroll
  for (int e0 = 0; e0 < 1536; e0 += 256) {
    int e = e0 + tid;
    int j = e >> 5, cc = e & 31;
    half8v val = (half8v)(_Float16)0.f;
    if (j < NT) {
      const _Float16* rp = token_row_ptr(j, wy, wx, b, qkv0, qkv1, qkv2);
      if (rp) val = *(const half8v*)(rp + 512 + cc * 8);
    }
    *(half8v*)&vrows[j][cc * 8] = val;
  }

  // --- Q/K fragments direct from global: tile t rows = tokens t*16 + i16
  half8v qf[3][2], kf[3][2];
#pragma unroll
  for (int t = 0; t < 3; ++t) {
    const _Float16* rp = token_row_ptr(t * 16 + i16, wy, wx, b, qkv0, qkv1, qkv2);
#pragma unroll
    for (int kc = 0; kc < 2; ++kc) {
      if (rp) {
        qf[t][kc] = *(const half8v*)(rp + h * HD + kc * 32 + q4 * 8);
        kf[t][kc] = *(const half8v*)(rp + 256 + h * HD + kc * 32 + q4 * 8);
      } else {
        qf[t][kc] = (half8v)(_Float16)0.f;
        kf[t][kc] = (half8v)(_Float16)0.f;
      }
    }
  }

  // --- QK^T: 9 tiles x 2 K-chunks
  floatx4 s[3][3] = {};
#pragma unroll
  for (int kc = 0; kc < 2; ++kc)
#pragma unroll
    for (int ti = 0; ti < 3; ++ti)
#pragma unroll
      for (int tj = 0; tj < 3; ++tj)
        s[ti][tj] = __builtin_amdgcn_mfma_f32_16x16x32_f16(qf[ti][kc], kf[tj][kc], s[ti][tj], 0, 0, 0);

  // --- pos bias + tile-pad mask (C layout: row = q4*4+r, col = i16)
#pragma unroll
  for (int ti = 0; ti < 3; ++ti)
#pragma unroll
    for (int tj = 0; tj < 3; ++tj)
#pragma unroll
      for (int r = 0; r < 4; ++r) {
        int i = ti * 16 + q4 * 4 + r;
        int j = tj * 16 + i16;
        if (j < NT) { if (i < NT) s[ti][tj][r] += pos[(h * NT + i) * NT + j]; }
        else s[ti][tj][r] = -INFINITY;
      }

  // --- softmax per row (3 regs + 16-lane shfl reduce), write P f16 to LDS (stride 60)
#pragma unroll
  for (int ti = 0; ti < 3; ++ti)
#pragma unroll
    for (int r = 0; r < 4; ++r) {
      float v0 = s[ti][0][r], v1 = s[ti][1][r], v2 = s[ti][2][r];
      float m = fmaxf(fmaxf(v0, v1), v2);
      m = fmaxf(m, __shfl_xor(m, 1));
      m = fmaxf(m, __shfl_xor(m, 2));
      m = fmaxf(m, __shfl_xor(m, 4));
      m = fmaxf(m, __shfl_xor(m, 8));
      float e0 = expf(v0 - m), e1 = expf(v1 - m), e2 = expf(v2 - m);
      float sum = e0 + e1 + e2;
      sum += __shfl_xor(sum, 1);
      sum += __shfl_xor(sum, 2);
      sum += __shfl_xor(sum, 4);
      sum += __shfl_xor(sum, 8);
      float inv = 1.f / sum;
      int i = ti * 16 + q4 * 4 + r;
      ps[h][i][ 0 + i16] = (_Float16)(e0 * inv);
      ps[h][i][16 + i16] = (_Float16)(e1 * inv);
      ps[h][i][32 + i16] = (_Float16)(e2 * inv);
    }

  __syncthreads();   // vrows ready for all waves (ps is wave-private)

  // --- PV: A = P (3 m-tiles), B = V^T built from row-major vrows (4 d-tiles); K = 32 + 16
  half8v vb0[4]; half4v vb1[4];
#pragma unroll
  for (int n = 0; n < 4; ++n) {
    int col = h * HD + n * 16 + i16;
#pragma unroll
    for (int kk = 0; kk < 8; ++kk) vb0[n][kk] = vrows[q4 * 8 + kk][col];
#pragma unroll
    for (int kk = 0; kk < 4; ++kk) vb1[n][kk] = vrows[32 + q4 * 4 + kk][col];
  }
  const size_t obase = ((size_t)(b * NWIN + w) * NT) * C + h * HD;
#pragma unroll
  for (int mt = 0; mt < 3; ++mt) {
    half8v pa0 = *(const half8v*)&ps[h][mt * 16 + i16][q4 * 8];
    half4v pa1 = *(const half4v*)&ps[h][mt * 16 + i16][32 + q4 * 4];
    floatx4 o[4] = {};
#pragma unroll
    for (int n = 0; n < 4; ++n) {
      o[n] = __builtin_amdgcn_mfma_f32_16x16x32_f16(pa0, vb0[n], o[n], 0, 0, 0);
      o[n] = __builtin_amdgcn_mfma_f32_16x16x16f16(pa1, vb1[n], o[n], 0, 0, 0);
    }
#pragma unroll
    for (int r = 0; r < 4; ++r) {
      int i = mt * 16 + q4 * 4 + r;
      if (i < NT) {
#pragma unroll
        for (int n = 0; n < 4; ++n)
          O[obase + (size_t)i * C + n * 16 + i16] = (_Float16)o[n][r];
      }
    }
  }
}

// ---------------- proj GEMM (f16 MFMA) + bias, transposed store Yt[(b*C+c)*RPB + w*35+j] ----------------
__global__ __launch_bounds__(256) void proj_gemm(const _Float16* __restrict__ A,  // (Mg, 256) f16 row-major
                                                 const float* __restrict__ W,     // (256, 256) row-major
                                                 const float* __restrict__ bias,
                                                 float* __restrict__ Yt, int Mg) {
  __shared__ __align__(16) char smem[128 * 69 * 4];   // max(As+Bs = 15360, Cs = 35328)
  _Float16 (*As)[40] = (_Float16(*)[40])smem;
  _Float16 (*Bs)[40] = (_Float16(*)[40])(smem + 128 * 40 * 2);
  float    (*Cs)[69] = (float(*)[69])smem;

  const int tid  = threadIdx.x;
  const int m0   = blockIdx.x * 128;
  const int n0   = blockIdx.y * 64;
  const int w    = tid >> 6;
  const int lane = tid & 63;
  const int quad = lane >> 4;
  const int mn   = lane & 15;

  floatx4 acc[2][4] = {};
  for (int k0 = 0; k0 < C; k0 += 32) {
    // stage A (f16 row-major): straight half8 copies
#pragma unroll
    for (int u = 0; u < 2; ++u) {
      int e = u * 256 + tid;           // 512 units: 128 m x 4 k-octs
      int m = e >> 2, k8 = e & 3;
      int row = min(m0 + m, Mg - 1);
      half8v va = *(const half8v*)&A[(size_t)row * C + k0 + 8 * k8];
      *(half8v*)&As[m][8 * k8] = va;
    }
    // stage B: wave w stages k-oct w for all 64 n; lane owns row n=lane, 8 k-strided reads,
    // one contiguous half8 (b128) write -> conflict-free
    {
      const float* wp = W + (size_t)(k0 + w * 8) * C + n0 + lane;
      float wv[8];
#pragma unroll
      for (int j = 0; j < 8; ++j) wv[j] = wp[(size_t)j * C];
      half8v hv;
#pragma unroll
      for (int j = 0; j < 8; ++j) hv[j] = (_Float16)wv[j];
      *(half8v*)&Bs[lane][w * 8] = hv;
    }
    __syncthreads();
    half8v a0 = *(const half8v*)&As[w * 32 + mn][quad * 8];
    half8v a1 = *(const half8v*)&As[w * 32 + 16 + mn][quad * 8];
#pragma unroll
    for (int ni = 0; ni < 4; ++ni) {
      half8v bf = *(const half8v*)&Bs[ni * 16 + mn][quad * 8];
      acc[0][ni] = __builtin_amdgcn_mfma_f32_16x16x32_f16(a0, bf, acc[0][ni], 0, 0, 0);
      acc[1][ni] = __builtin_amdgcn_mfma_f32_16x16x32_f16(a1, bf, acc[1][ni], 0, 0, 0);
    }
    __syncthreads();   // also protects As/Bs before Cs aliasing overwrite
  }

  // epilogue: bias add into Cs, then transposed coalesced store
#pragma unroll
  for (int mi = 0; mi < 2; ++mi)
#pragma unroll
    for (int r = 0; r < 4; ++r)
#pragma unroll
      for (int ni = 0; ni < 4; ++ni)
        Cs[w * 32 + mi * 16 + quad * 4 + r][ni * 16 + mn] =
            acc[mi][ni][r] + bias[n0 + ni * 16 + mn];
  __syncthreads();
#pragma unroll
  for (int u = 0; u < 32; ++u) {
    int e = u * 256 + tid;            // 8192 elems: 128 m x 64 n
    int ml = e & 127, cl = e >> 7;
    int m = m0 + ml;
    if (m < Mg) {
      int bb = m / RPB;
      int r = m - bb * RPB;
      Yt[((size_t)bb * C + n0 + cl) * RPB + r] = Cs[ml][cl];
    }
  }
}

// ---------------- fold (gather form), group-local ----------------
__global__ __launch_bounds__(256) void fold_kernel(const float* __restrict__ Yt,
                                                   float* __restrict__ out,
                                                   int k_, int s_, int p_, int H_,
                                                   int toff, int total) {
  int idx = blockIdx.x * 256 + threadIdx.x;
  if (idx >= total) return;
  int x = idx % H_;
  int y = (idx / H_) % H_;
  int c = (idx / (H_ * H_)) % C;
  int b = idx / (C * H_ * H_);
  int py = y + p_, px = x + p_;
  int ay = py - k_ + 1;
  int wy_lo = ay <= 0 ? 0 : (ay + s_ - 1) / s_;
  int wy_hi = min(19, py / s_);
  int ax = px - k_ + 1;
  int wx_lo = ax <= 0 ? 0 : (ax + s_ - 1) / s_;
  int wx_hi = min(19, px / s_);
  const float* base = Yt + ((size_t)b * C + c) * RPB;
  float acc = 0.f;
  for (int wy = wy_lo; wy <= wy_hi; ++wy) {
    int tyy = py - wy * s_;
    for (int wx = wx_lo; wx <= wx_hi; ++wx) {
      int txx = px - wx * s_;
      acc += base[(wy * 20 + wx) * NT + toff + tyy * k_ + txx];
    }
  }
  out[idx] = acc;
}

} // namespace

extern "C" void kernel_launch(void* const* d_in, const int* in_sizes, int n_in,
                              void* d_out, int out_size, void* d_ws, size_t ws_size,
                              hipStream_t stream) {
  const float* x0    = (const float*)d_in[0];
  const float* x1    = (const float*)d_in[1];
  const float* x2    = (const float*)d_in[2];
  const float* wq0   = (const float*)d_in[3];
  const float* wq1   = (const float*)d_in[4];
  const float* wq2   = (const float*)d_in[5];
  const float* wproj = (const float*)d_in[6];
  const float* bproj = (const float*)d_in[7];
  const float* rpb   = (const float*)d_in[8];
  const float* ab    = (const float*)d_in[9];
  float* out = (float*)d_out;

  // pick largest batch-group size g in {8,4,2,1} that fits ws_size
  int g = 8;
  while (g > 1 && POS_B + (size_t)g * PB_B > ws_size) g >>= 1;

  char* ws = (char*)d_ws;
  float*    posb  = (float*)ws;
  _Float16* qkv0g = (_Float16*)(ws + POS_B);
  _Float16* qkv1g = qkv0g + (size_t)g * 6400 * QKVN;
  _Float16* qkv2g = qkv1g + (size_t)g * 1600 * QKVN;
  _Float16* oatt  = qkv2g + (size_t)g *  400 * QKVN;
  float*    yt    = (float*)(ws + POS_B + (size_t)g * (QKV_B + OATT_B));

  pos_kernel<<<(NH * NT * NT + 255) / 256, 256, 0, stream>>>(rpb, ab, posb);

  const size_t off1 = (size_t)B * C * 6400;
  const size_t off2 = off1 + (size_t)B * C * 1600;

  for (int b0 = 0; b0 < B; b0 += g) {
    const float* x0g = x0 + (size_t)b0 * C * 6400;
    const float* x1g = x1 + (size_t)b0 * C * 1600;
    const float* x2g = x2 + (size_t)b0 * C * 400;

    qkv_gemm<<<dim3((g * 6400 + 127) / 128, QKVN / 128), 256, 0, stream>>>(x0g, wq0, qkv0g, 6400, g * 6400, 512);
    qkv_gemm<<<dim3((g * 1600 + 127) / 128, QKVN / 128), 256, 0, stream>>>(x1g, wq1, qkv1g, 1600, g * 1600, 512);
    qkv_gemm<<<dim3((g *  400 + 127) / 128, QKVN / 128), 256, 0, stream>>>(x2g, wq2, qkv2g,  400, g *  400, 512);

    attn_kernel<<<g * NWIN, 256, 0, stream>>>(qkv0g, qkv1g, qkv2g, posb, oatt);

    proj_gemm<<<dim3((g * RPB + 127) / 128, C / 64), 256, 0, stream>>>(oatt, wproj, bproj, yt, g * RPB);

    const int tot0 = g * C * 6400;
    const int tot1 = g * C * 1600;
    const int tot2 = g * C * 400;
    fold_kernel<<<(tot0 + 255) / 256, 256, 0, stream>>>(yt, out + (size_t)b0 * C * 6400,        5, 4, 2, 80, 0,  tot0);
    fold_kernel<<<(tot1 + 255) / 256, 256, 0, stream>>>(yt, out + off1 + (size_t)b0 * C * 1600, 3, 2, 1, 40, 25, tot1);
    fold_kernel<<<(tot2 + 255) / 256, 256, 0, stream>>>(yt, out + off2 + (size_t)b0 * C * 400,  1, 1, 0, 20, 34, tot2);
  }
}

// Round 4
// 493.461 us; speedup vs baseline: 1.5024x; 1.0454x over previous
//
#include <hip/hip_runtime.h>
#include <math.h>

namespace {

typedef _Float16 half8v __attribute__((ext_vector_type(8)));
typedef _Float16 half4v __attribute__((ext_vector_type(4)));
typedef float    floatx4 __attribute__((ext_vector_type(4)));

constexpr int B   = 8;
constexpr int C   = 256;
constexpr int NH  = 4;
constexpr int HD  = 64;
constexpr int NWIN = 400;   // 20x20 windows per level
constexpr int NT  = 35;     // 25 + 9 + 1 tokens per window
constexpr int QKVN = 768;
constexpr int RPB = NWIN * NT;  // 14,000 token-rows per batch

// per-batch byte counts for workspace
constexpr size_t QKV_B  = (size_t)8400 * QKVN * 2;   // 12,902,400  (f16)
constexpr size_t OATT_B = (size_t)RPB * C * 2;       //  7,168,000  (f16)
constexpr size_t YT_B   = (size_t)RPB * C * 4;       // 14,336,000  (f32)
constexpr size_t PB_B   = QKV_B + OATT_B + YT_B;     // 34,406,400
constexpr size_t POS_B  = 19712;                     // 4900 f32, padded

__device__ inline unsigned pack2(float a, float b) {
  union { _Float16 h[2]; unsigned u; } x;
  x.h[0] = (_Float16)a; x.h[1] = (_Float16)b;
  return x.u;
}

// ---------------- pos table ----------------
__device__ inline void token_coord(int j, double& cy, double& cx) {
  if (j < 25)      { int ty = j / 5,  tx = j % 5;  cy = (double)(ty - 2); cx = (double)(tx - 2); }
  else if (j < 34) { int t = j - 25; int ty = t / 3, tx = t % 3;
                     cy = (double)(ty - 1) * (5.0 / 3.0); cx = (double)(tx - 1) * (5.0 / 3.0); }
  else             { cy = 0.0; cx = 0.0; }
}

__global__ void pos_kernel(const float* __restrict__ rpb, const float* __restrict__ ab,
                           float* __restrict__ pos) {
  int p = blockIdx.x * blockDim.x + threadIdx.x;
  if (p >= NH * NT * NT) return;
  int j = p % NT, i = (p / NT) % NT, h = p / (NT * NT);
  double cyi, cxi, cyj, cxj;
  token_coord(i, cyi, cxi);
  token_coord(j, cyj, cxj);
  float fidx = (float)(((cyi - cyj) + 4.0) * 9.0 + ((cxi - cxj) + 4.0));
  int fl = min(max((int)floorf(fidx), 0), 80);
  int ce = min(max((int)ceilf(fidx), 0), 80);
  float w = fidx - (float)fl;
  float pv = (1.0f - w) * rpb[fl * NH + h] + w * rpb[ce * NH + h];
  int li = (i < 25) ? 0 : ((i < 34) ? 1 : 2);
  pos[p] = pv + ab[li * NH + h];
}

// ---------------- QKV GEMM (f16 MFMA, 128x128 tile): Y[m, 768](f16) = X^T @ W ----------------
__global__ __launch_bounds__(256) void qkv_gemm(const float* __restrict__ X,
                                                const float* __restrict__ W,
                                                _Float16* __restrict__ Y,
                                                int HW, int Mg, int normN) {
  __shared__ _Float16 As[128][40];   // row 80B, 16B-aligned frag reads
  __shared__ _Float16 Bs[128][40];
  const int tid  = threadIdx.x;
  const int m0   = blockIdx.x * 128;
  const int n0   = blockIdx.y * 128;
  const int w    = tid >> 6;
  const int lane = tid & 63;
  const int quad = lane >> 4;
  const int mn   = lane & 15;

  floatx4 acc[2][8] = {};
  for (int k0 = 0; k0 < C; k0 += 32) {
    // chunk c in 0..7: (half = c>>2) x (k-oct = c&3); wave w stages chunks {2w, 2w+1}
    float av[2][8], bv[2][8];
    int rl[2];
#pragma unroll
    for (int u = 0; u < 2; ++u) {
      int c = w * 2 + u;
      int ko = c & 3;
      rl[u] = (c >> 2) * 64 + lane;
      // A: X is [C][HW] per batch; row gm of A = pixel, col = channel
      int gm = min(m0 + rl[u], Mg - 1);
      int bb = gm / HW, pix = gm - bb * HW;
      const float* xp = X + ((size_t)bb * C + k0 + ko * 8) * HW + pix;
#pragma unroll
      for (int j = 0; j < 8; ++j) av[u][j] = xp[(size_t)j * HW];
      // B: W is [K][QKVN] row-major
      const float* wp = W + (size_t)(k0 + ko * 8) * QKVN + n0 + rl[u];
#pragma unroll
      for (int j = 0; j < 8; ++j) bv[u][j] = wp[(size_t)j * QKVN];
    }
#pragma unroll
    for (int u = 0; u < 2; ++u) {
      int ko = (w * 2 + u) & 3;
      half8v ha, hb;
#pragma unroll
      for (int j = 0; j < 8; ++j) { ha[j] = (_Float16)av[u][j]; hb[j] = (_Float16)bv[u][j]; }
      *(half8v*)&As[rl[u]][ko * 8] = ha;
      *(half8v*)&Bs[rl[u]][ko * 8] = hb;
    }
    __syncthreads();
    half8v a0 = *(const half8v*)&As[w * 32 + mn][quad * 8];
    half8v a1 = *(const half8v*)&As[w * 32 + 16 + mn][quad * 8];
#pragma unroll
    for (int ni = 0; ni < 8; ++ni) {
      half8v bf = *(const half8v*)&Bs[ni * 16 + mn][quad * 8];
      acc[0][ni] = __builtin_amdgcn_mfma_f32_16x16x32_f16(a0, bf, acc[0][ni], 0, 0, 0);
      acc[1][ni] = __builtin_amdgcn_mfma_f32_16x16x32_f16(a1, bf, acc[1][ni], 0, 0, 0);
    }
    __syncthreads();
  }

  // epilogue: per-row L2 norm per 64-col head section (two sections per 128-tile)
  const bool do_norm = (n0 < normN);
#pragma unroll
  for (int mi = 0; mi < 2; ++mi) {
#pragma unroll
    for (int r = 0; r < 4; ++r) {
      float s0 = 0.f, s1 = 0.f;
#pragma unroll
      for (int ni = 0; ni < 4; ++ni) { float vv = acc[mi][ni][r]; s0 += vv * vv; }
#pragma unroll
      for (int ni = 4; ni < 8; ++ni) { float vv = acc[mi][ni][r]; s1 += vv * vv; }
      s0 += __shfl_xor(s0, 1); s1 += __shfl_xor(s1, 1);
      s0 += __shfl_xor(s0, 2); s1 += __shfl_xor(s1, 2);
      s0 += __shfl_xor(s0, 4); s1 += __shfl_xor(s1, 4);
      s0 += __shfl_xor(s0, 8); s1 += __shfl_xor(s1, 8);
      float sc0 = do_norm ? (1.f / fmaxf(sqrtf(s0), 1e-12f)) : 1.f;
      float sc1 = do_norm ? (1.f / fmaxf(sqrtf(s1), 1e-12f)) : 1.f;
      int row = m0 + w * 32 + mi * 16 + quad * 4 + r;
      if (row < Mg) {
#pragma unroll
        for (int ni = 0; ni < 8; ++ni)
          Y[(size_t)row * QKVN + n0 + ni * 16 + mn] =
              (_Float16)(acc[mi][ni][r] * (ni < 4 ? sc0 : sc1));
      }
    }
  }
}

// ---------------- attention: swapped-operand MFMA version. Block = (b, window); wave = head. ----------------
// S^T = mfma(K, Q): lane (i16,q4) holds S^T[j=tj*16+q4*4+r][i=ti*16+i16] = P[i][j] in exactly
// the A-fragment layout of mfma_f32_16x16x16_f16. Softmax is fully in-register (12 regs/lane
// per i-tile + shfl_xor 16/32 across the 4 q4 copies) -> no P LDS at all. V staged row-major
// cooperatively; row stride 260 halfs (130 words == 2 mod 8) makes the 4-row-strided scalar
// column reads for B-frags a perfect 32-bank partition. LDS = 25 KB -> high occupancy.
__device__ inline const _Float16* token_row_ptr(int j, int wy, int wx, int b,
                                                const _Float16* q0, const _Float16* q1,
                                                const _Float16* q2) {
  if (j >= NT) return nullptr;
  int k_, s_, p_, Hl, t; const _Float16* base;
  if (j < 25)      { k_ = 5; s_ = 4; p_ = 2; Hl = 80; t = j;      base = q0; }
  else if (j < 34) { k_ = 3; s_ = 2; p_ = 1; Hl = 40; t = j - 25; base = q1; }
  else             { k_ = 1; s_ = 1; p_ = 0; Hl = 20; t = 0;      base = q2; }
  int ty = t / k_, tx = t % k_;
  int y = wy * s_ + ty - p_;
  int x = wx * s_ + tx - p_;
  if ((unsigned)y >= (unsigned)Hl || (unsigned)x >= (unsigned)Hl) return nullptr;
  return base + ((size_t)b * Hl * Hl + (size_t)y * Hl + x) * QKVN;
}

__global__ __launch_bounds__(256, 4) void attn_kernel(const _Float16* __restrict__ qkv0,
                                                      const _Float16* __restrict__ qkv1,
                                                      const _Float16* __restrict__ qkv2,
                                                      const float* __restrict__ pos,
                                                      _Float16* __restrict__ O) {
  const int blk = blockIdx.x;               // b*NWIN + w
  const int w   = blk % NWIN;
  const int b   = blk / NWIN;
  const int wy = w / 20, wx = w % 20;
  const int tid  = threadIdx.x;
  const int h    = tid >> 6;                // wave = head
  const int lane = tid & 63;
  const int i16  = lane & 15;
  const int q4   = lane >> 4;

  __shared__ __align__(16) _Float16 vrows[48][260];   // V row-major, all heads; rows 35..47 zero

  // --- cooperative V staging: 1536 half8-chunks = 48 rows x 32 chunks over 256 threads
#pragma unroll
  for (int e0 = 0; e0 < 1536; e0 += 256) {
    int e = e0 + tid;
    int j = e >> 5, cc = e & 31;
    half8v val = (half8v)(_Float16)0.f;
    if (j < NT) {
      const _Float16* rp = token_row_ptr(j, wy, wx, b, qkv0, qkv1, qkv2);
      if (rp) val = *(const half8v*)(rp + 512 + cc * 8);
    }
    *(half8v*)&vrows[j][cc * 8] = val;
  }

  // --- Q/K fragments direct from global: tile t rows = tokens t*16 + i16
  half8v qf[3][2], kf[3][2];
#pragma unroll
  for (int t = 0; t < 3; ++t) {
    const _Float16* rp = token_row_ptr(t * 16 + i16, wy, wx, b, qkv0, qkv1, qkv2);
#pragma unroll
    for (int kc = 0; kc < 2; ++kc) {
      if (rp) {
        qf[t][kc] = *(const half8v*)(rp + h * HD + kc * 32 + q4 * 8);
        kf[t][kc] = *(const half8v*)(rp + 256 + h * HD + kc * 32 + q4 * 8);
      } else {
        qf[t][kc] = (half8v)(_Float16)0.f;
        kf[t][kc] = (half8v)(_Float16)0.f;
      }
    }
  }

  // --- swapped QK^T: s[tj][ti][r] = S^T[j=tj*16+q4*4+r][i=ti*16+i16]
  floatx4 s[3][3] = {};
#pragma unroll
  for (int kc = 0; kc < 2; ++kc)
#pragma unroll
    for (int tj = 0; tj < 3; ++tj)
#pragma unroll
      for (int ti = 0; ti < 3; ++ti)
        s[tj][ti] = __builtin_amdgcn_mfma_f32_16x16x32_f16(kf[tj][kc], qf[ti][kc], s[tj][ti], 0, 0, 0);

  // --- pos bias + tile-pad mask (j >= NT -> -inf; tj=0 rows are never masked so max stays finite)
#pragma unroll
  for (int tj = 0; tj < 3; ++tj)
#pragma unroll
    for (int ti = 0; ti < 3; ++ti)
#pragma unroll
      for (int r = 0; r < 4; ++r) {
        int j = tj * 16 + q4 * 4 + r;
        int i = ti * 16 + i16;
        if (j < NT) { if (i < NT) s[tj][ti][r] += pos[(h * NT + i) * NT + j]; }
        else s[tj][ti][r] = -INFINITY;
      }

  // --- in-register softmax over j per query i (col i16): 12 local regs + shfl_xor 16/32
  half4v pa[3][3];   // [tj][ti] = A-frag of P for PV (16x16x16 layout)
#pragma unroll
  for (int ti = 0; ti < 3; ++ti) {
    float m = s[0][ti][0];
#pragma unroll
    for (int tj = 0; tj < 3; ++tj)
#pragma unroll
      for (int r = 0; r < 4; ++r) m = fmaxf(m, s[tj][ti][r]);
    m = fmaxf(m, __shfl_xor(m, 16));
    m = fmaxf(m, __shfl_xor(m, 32));
    float sum = 0.f;
#pragma unroll
    for (int tj = 0; tj < 3; ++tj)
#pragma unroll
      for (int r = 0; r < 4; ++r) { float e = expf(s[tj][ti][r] - m); s[tj][ti][r] = e; sum += e; }
    sum += __shfl_xor(sum, 16);
    sum += __shfl_xor(sum, 32);
    float inv = 1.f / sum;
#pragma unroll
    for (int tj = 0; tj < 3; ++tj)
#pragma unroll
      for (int r = 0; r < 4; ++r) pa[tj][ti][r] = (_Float16)(s[tj][ti][r] * inv);
  }

  __syncthreads();   // vrows ready for all waves

  // --- V B-frags for 16x16x16: lane holds V[j=tj*16+q4*4+kk][d=n*16+i16] (this head's cols)
  half4v vb[3][4];
#pragma unroll
  for (int tj = 0; tj < 3; ++tj)
#pragma unroll
    for (int n = 0; n < 4; ++n)
#pragma unroll
      for (int kk = 0; kk < 4; ++kk)
        vb[tj][n][kk] = vrows[tj * 16 + q4 * 4 + kk][h * HD + n * 16 + i16];

  // --- PV: O[i][d] accumulated over 3 j-chunks of 16; C layout row=q4*4+r (i), col=i16 (d)
  const size_t obase = ((size_t)(b * NWIN + w) * NT) * C + h * HD;
#pragma unroll
  for (int ti = 0; ti < 3; ++ti) {
    floatx4 o[4] = {};
#pragma unroll
    for (int tj = 0; tj < 3; ++tj)
#pragma unroll
      for (int n = 0; n < 4; ++n)
        o[n] = __builtin_amdgcn_mfma_f32_16x16x16f16(pa[tj][ti], vb[tj][n], o[n], 0, 0, 0);
#pragma unroll
    for (int r = 0; r < 4; ++r) {
      int i = ti * 16 + q4 * 4 + r;
      if (i < NT) {
#pragma unroll
        for (int n = 0; n < 4; ++n)
          O[obase + (size_t)i * C + n * 16 + i16] = (_Float16)o[n][r];
      }
    }
  }
}

// ---------------- proj GEMM (f16 MFMA) + bias, transposed store Yt[(b*C+c)*RPB + w*35+j] ----------------
__global__ __launch_bounds__(256) void proj_gemm(const _Float16* __restrict__ A,  // (Mg, 256) f16 row-major
                                                 const float* __restrict__ W,     // (256, 256) row-major
                                                 const float* __restrict__ bias,
                                                 float* __restrict__ Yt, int Mg) {
  __shared__ __align__(16) char smem[128 * 69 * 4];   // max(As+Bs = 15360, Cs = 35328)
  _Float16 (*As)[40] = (_Float16(*)[40])smem;
  _Float16 (*Bs)[40] = (_Float16(*)[40])(smem + 128 * 40 * 2);
  float    (*Cs)[69] = (float(*)[69])smem;

  const int tid  = threadIdx.x;
  const int m0   = blockIdx.x * 128;
  const int n0   = blockIdx.y * 64;
  const int w    = tid >> 6;
  const int lane = tid & 63;
  const int quad = lane >> 4;
  const int mn   = lane & 15;

  floatx4 acc[2][4] = {};
  for (int k0 = 0; k0 < C; k0 += 32) {
    // stage A (f16 row-major): straight half8 copies
#pragma unroll
    for (int u = 0; u < 2; ++u) {
      int e = u * 256 + tid;           // 512 units: 128 m x 4 k-octs
      int m = e >> 2, k8 = e & 3;
      int row = min(m0 + m, Mg - 1);
      half8v va = *(const half8v*)&A[(size_t)row * C + k0 + 8 * k8];
      *(half8v*)&As[m][8 * k8] = va;
    }
    // stage B: wave w stages k-oct w for all 64 n; lane owns row n=lane, 8 k-strided reads,
    // one contiguous half8 (b128) write -> conflict-free
    {
      const float* wp = W + (size_t)(k0 + w * 8) * C + n0 + lane;
      float wv[8];
#pragma unroll
      for (int j = 0; j < 8; ++j) wv[j] = wp[(size_t)j * C];
      half8v hv;
#pragma unroll
      for (int j = 0; j < 8; ++j) hv[j] = (_Float16)wv[j];
      *(half8v*)&Bs[lane][w * 8] = hv;
    }
    __syncthreads();
    half8v a0 = *(const half8v*)&As[w * 32 + mn][quad * 8];
    half8v a1 = *(const half8v*)&As[w * 32 + 16 + mn][quad * 8];
#pragma unroll
    for (int ni = 0; ni < 4; ++ni) {
      half8v bf = *(const half8v*)&Bs[ni * 16 + mn][quad * 8];
      acc[0][ni] = __builtin_amdgcn_mfma_f32_16x16x32_f16(a0, bf, acc[0][ni], 0, 0, 0);
      acc[1][ni] = __builtin_amdgcn_mfma_f32_16x16x32_f16(a1, bf, acc[1][ni], 0, 0, 0);
    }
    __syncthreads();   // also protects As/Bs before Cs aliasing overwrite
  }

  // epilogue: bias add into Cs, then transposed coalesced store
#pragma unroll
  for (int mi = 0; mi < 2; ++mi)
#pragma unroll
    for (int r = 0; r < 4; ++r)
#pragma unroll
      for (int ni = 0; ni < 4; ++ni)
        Cs[w * 32 + mi * 16 + quad * 4 + r][ni * 16 + mn] =
            acc[mi][ni][r] + bias[n0 + ni * 16 + mn];
  __syncthreads();
#pragma unroll
  for (int u = 0; u < 32; ++u) {
    int e = u * 256 + tid;            // 8192 elems: 128 m x 64 n
    int ml = e & 127, cl = e >> 7;
    int m = m0 + ml;
    if (m < Mg) {
      int bb = m / RPB;
      int r = m - bb * RPB;
      Yt[((size_t)bb * C + n0 + cl) * RPB + r] = Cs[ml][cl];
    }
  }
}

// ---------------- fold (gather form), group-local ----------------
__global__ __launch_bounds__(256) void fold_kernel(const float* __restrict__ Yt,
                                                   float* __restrict__ out,
                                                   int k_, int s_, int p_, int H_,
                                                   int toff, int total) {
  int idx = blockIdx.x * 256 + threadIdx.x;
  if (idx >= total) return;
  int x = idx % H_;
  int y = (idx / H_) % H_;
  int c = (idx / (H_ * H_)) % C;
  int b = idx / (C * H_ * H_);
  int py = y + p_, px = x + p_;
  int ay = py - k_ + 1;
  int wy_lo = ay <= 0 ? 0 : (ay + s_ - 1) / s_;
  int wy_hi = min(19, py / s_);
  int ax = px - k_ + 1;
  int wx_lo = ax <= 0 ? 0 : (ax + s_ - 1) / s_;
  int wx_hi = min(19, px / s_);
  const float* base = Yt + ((size_t)b * C + c) * RPB;
  float acc = 0.f;
  for (int wy = wy_lo; wy <= wy_hi; ++wy) {
    int tyy = py - wy * s_;
    for (int wx = wx_lo; wx <= wx_hi; ++wx) {
      int txx = px - wx * s_;
      acc += base[(wy * 20 + wx) * NT + toff + tyy * k_ + txx];
    }
  }
  out[idx] = acc;
}

} // namespace

extern "C" void kernel_launch(void* const* d_in, const int* in_sizes, int n_in,
                              void* d_out, int out_size, void* d_ws, size_t ws_size,
                              hipStream_t stream) {
  const float* x0    = (const float*)d_in[0];
  const float* x1    = (const float*)d_in[1];
  const float* x2    = (const float*)d_in[2];
  const float* wq0   = (const float*)d_in[3];
  const float* wq1   = (const float*)d_in[4];
  const float* wq2   = (const float*)d_in[5];
  const float* wproj = (const float*)d_in[6];
  const float* bproj = (const float*)d_in[7];
  const float* rpb   = (const float*)d_in[8];
  const float* ab    = (const float*)d_in[9];
  float* out = (float*)d_out;

  // pick largest batch-group size g in {8,4,2,1} that fits ws_size
  int g = 8;
  while (g > 1 && POS_B + (size_t)g * PB_B > ws_size) g >>= 1;

  char* ws = (char*)d_ws;
  float*    posb  = (float*)ws;
  _Float16* qkv0g = (_Float16*)(ws + POS_B);
  _Float16* qkv1g = qkv0g + (size_t)g * 6400 * QKVN;
  _Float16* qkv2g = qkv1g + (size_t)g * 1600 * QKVN;
  _Float16* oatt  = qkv2g + (size_t)g *  400 * QKVN;
  float*    yt    = (float*)(ws + POS_B + (size_t)g * (QKV_B + OATT_B));

  pos_kernel<<<(NH * NT * NT + 255) / 256, 256, 0, stream>>>(rpb, ab, posb);

  const size_t off1 = (size_t)B * C * 6400;
  const size_t off2 = off1 + (size_t)B * C * 1600;

  for (int b0 = 0; b0 < B; b0 += g) {
    const float* x0g = x0 + (size_t)b0 * C * 6400;
    const float* x1g = x1 + (size_t)b0 * C * 1600;
    const float* x2g = x2 + (size_t)b0 * C * 400;

    qkv_gemm<<<dim3((g * 6400 + 127) / 128, QKVN / 128), 256, 0, stream>>>(x0g, wq0, qkv0g, 6400, g * 6400, 512);
    qkv_gemm<<<dim3((g * 1600 + 127) / 128, QKVN / 128), 256, 0, stream>>>(x1g, wq1, qkv1g, 1600, g * 1600, 512);
    qkv_gemm<<<dim3((g *  400 + 127) / 128, QKVN / 128), 256, 0, stream>>>(x2g, wq2, qkv2g,  400, g *  400, 512);

    attn_kernel<<<g * NWIN, 256, 0, stream>>>(qkv0g, qkv1g, qkv2g, posb, oatt);

    proj_gemm<<<dim3((g * RPB + 127) / 128, C / 64), 256, 0, stream>>>(oatt, wproj, bproj, yt, g * RPB);

    const int tot0 = g * C * 6400;
    const int tot1 = g * C * 1600;
    const int tot2 = g * C * 400;
    fold_kernel<<<(tot0 + 255) / 256, 256, 0, stream>>>(yt, out + (size_t)b0 * C * 6400,        5, 4, 2, 80, 0,  tot0);
    fold_kernel<<<(tot1 + 255) / 256, 256, 0, stream>>>(yt, out + off1 + (size_t)b0 * C * 1600, 3, 2, 1, 40, 25, tot1);
    fold_kernel<<<(tot2 + 255) / 256, 256, 0, stream>>>(yt, out + off2 + (size_t)b0 * C * 400,  1, 1, 0, 20, 34, tot2);
  }
}

// Round 5
// 456.550 us; speedup vs baseline: 1.6239x; 1.0808x over previous
//
#include <hip/hip_runtime.h>
#include <math.h>

namespace {

typedef _Float16 half8v __attribute__((ext_vector_type(8)));
typedef _Float16 half4v __attribute__((ext_vector_type(4)));
typedef float    floatx4 __attribute__((ext_vector_type(4)));

constexpr int B   = 8;
constexpr int C   = 256;
constexpr int NH  = 4;
constexpr int HD  = 64;
constexpr int NWIN = 400;   // 20x20 windows per level
constexpr int NT  = 35;     // 25 + 9 + 1 tokens per window
constexpr int QKVN = 768;
constexpr int RPB = NWIN * NT;  // 14,000 token-rows per batch

// per-batch byte counts for workspace
constexpr size_t QKV_B  = (size_t)8400 * QKVN * 2;   // 12,902,400  (f16)
constexpr size_t OATT_B = (size_t)RPB * C * 2;       //  7,168,000  (f16)
constexpr size_t YT_B   = (size_t)RPB * C * 4;       // 14,336,000  (f32)
constexpr size_t PB_B   = QKV_B + OATT_B + YT_B;     // 34,406,400
constexpr size_t POS_B  = 19712;                     // 4900 f32, padded

// ---------------- pos table ----------------
__device__ inline void token_coord(int j, double& cy, double& cx) {
  if (j < 25)      { int ty = j / 5,  tx = j % 5;  cy = (double)(ty - 2); cx = (double)(tx - 2); }
  else if (j < 34) { int t = j - 25; int ty = t / 3, tx = t % 3;
                     cy = (double)(ty - 1) * (5.0 / 3.0); cx = (double)(tx - 1) * (5.0 / 3.0); }
  else             { cy = 0.0; cx = 0.0; }
}

__global__ void pos_kernel(const float* __restrict__ rpb, const float* __restrict__ ab,
                           float* __restrict__ pos) {
  int p = blockIdx.x * blockDim.x + threadIdx.x;
  if (p >= NH * NT * NT) return;
  int j = p % NT, i = (p / NT) % NT, h = p / (NT * NT);
  double cyi, cxi, cyj, cxj;
  token_coord(i, cyi, cxi);
  token_coord(j, cyj, cxj);
  float fidx = (float)(((cyi - cyj) + 4.0) * 9.0 + ((cxi - cxj) + 4.0));
  int fl = min(max((int)floorf(fidx), 0), 80);
  int ce = min(max((int)ceilf(fidx), 0), 80);
  float w = fidx - (float)fl;
  float pv = (1.0f - w) * rpb[fl * NH + h] + w * rpb[ce * NH + h];
  int li = (i < 25) ? 0 : ((i < 34) ? 1 : 2);
  pos[p] = pv + ab[li * NH + h];
}

// ---------------- fused QKV GEMM (f16 MFMA, 128x128 tile, all 3 levels, reg-prefetch) ----------
// Y[m, 768](f16) = X^T @ W per level; level picked from blockIdx.x range (wave-uniform).
// K-loop software pipeline: global loads for step t+1 issue right after the first barrier of
// step t, flying under frag-reads+MFMA; vmcnt-wait lands at step t+1's LDS write.
// Epilogue: L2-normalize each output row per 64-col head section when n0 < 512 (q,k).
__global__ __launch_bounds__(256) void qkv_gemm(const float* __restrict__ X0,
                                                const float* __restrict__ X1,
                                                const float* __restrict__ X2,
                                                const float* __restrict__ W0,
                                                const float* __restrict__ W1,
                                                const float* __restrict__ W2,
                                                _Float16* __restrict__ Y0,
                                                _Float16* __restrict__ Y1,
                                                _Float16* __restrict__ Y2,
                                                int mb0, int mb01, int g) {
  __shared__ _Float16 As[128][40];   // row 80B, 16B-aligned frag reads
  __shared__ _Float16 Bs[128][40];

  int mblk = blockIdx.x;
  const float* X; const float* W; _Float16* Y; int HW;
  if (mblk < mb0)       { X = X0; W = W0; Y = Y0; HW = 6400; }
  else if (mblk < mb01) { X = X1; W = W1; Y = Y1; HW = 1600; mblk -= mb0; }
  else                  { X = X2; W = W2; Y = Y2; HW =  400; mblk -= mb01; }
  const int Mg = g * HW;

  const int tid  = threadIdx.x;
  const int m0   = mblk * 128;
  const int n0   = blockIdx.y * 128;
  const int w    = tid >> 6;
  const int lane = tid & 63;
  const int quad = lane >> 4;
  const int mn   = lane & 15;

  // staging geometry (k-invariant): chunk c = w*2+u -> (half = c>>2) x (k-oct = c&3)
  int rl[2], koA[2];
  const float* abase[2];
  const float* bbase[2];
#pragma unroll
  for (int u = 0; u < 2; ++u) {
    int c = w * 2 + u;
    int ko = c & 3; koA[u] = ko;
    rl[u] = (c >> 2) * 64 + lane;
    int gm = min(m0 + rl[u], Mg - 1);
    int bb = gm / HW, pix = gm - bb * HW;
    abase[u] = X + ((size_t)bb * C + ko * 8) * HW + pix;
    bbase[u] = W + (size_t)(ko * 8) * QKVN + n0 + rl[u];
  }

  float av[2][8], bv[2][8];
  auto LOAD = [&](int k0) {
#pragma unroll
    for (int u = 0; u < 2; ++u) {
      const float* xp = abase[u] + (size_t)k0 * HW;
      const float* wp = bbase[u] + (size_t)k0 * QKVN;
#pragma unroll
      for (int j = 0; j < 8; ++j) { av[u][j] = xp[(size_t)j * HW]; bv[u][j] = wp[(size_t)j * QKVN]; }
    }
  };

  LOAD(0);
  floatx4 acc[2][8] = {};
  for (int k0 = 0; k0 < C; k0 += 32) {
#pragma unroll
    for (int u = 0; u < 2; ++u) {
      half8v ha, hb;
#pragma unroll
      for (int j = 0; j < 8; ++j) { ha[j] = (_Float16)av[u][j]; hb[j] = (_Float16)bv[u][j]; }
      *(half8v*)&As[rl[u]][koA[u] * 8] = ha;
      *(half8v*)&Bs[rl[u]][koA[u] * 8] = hb;
    }
    __syncthreads();
    if (k0 + 32 < C) LOAD(k0 + 32);   // prefetch next K-step under MFMA
    half8v a0 = *(const half8v*)&As[w * 32 + mn][quad * 8];
    half8v a1 = *(const half8v*)&As[w * 32 + 16 + mn][quad * 8];
#pragma unroll
    for (int ni = 0; ni < 8; ++ni) {
      half8v bf = *(const half8v*)&Bs[ni * 16 + mn][quad * 8];
      acc[0][ni] = __builtin_amdgcn_mfma_f32_16x16x32_f16(a0, bf, acc[0][ni], 0, 0, 0);
      acc[1][ni] = __builtin_amdgcn_mfma_f32_16x16x32_f16(a1, bf, acc[1][ni], 0, 0, 0);
    }
    __syncthreads();
  }

  // epilogue: per-row L2 norm per 64-col head section (two sections per 128-tile)
  const bool do_norm = (n0 < 512);
#pragma unroll
  for (int mi = 0; mi < 2; ++mi) {
#pragma unroll
    for (int r = 0; r < 4; ++r) {
      float s0 = 0.f, s1 = 0.f;
#pragma unroll
      for (int ni = 0; ni < 4; ++ni) { float vv = acc[mi][ni][r]; s0 += vv * vv; }
#pragma unroll
      for (int ni = 4; ni < 8; ++ni) { float vv = acc[mi][ni][r]; s1 += vv * vv; }
      s0 += __shfl_xor(s0, 1); s1 += __shfl_xor(s1, 1);
      s0 += __shfl_xor(s0, 2); s1 += __shfl_xor(s1, 2);
      s0 += __shfl_xor(s0, 4); s1 += __shfl_xor(s1, 4);
      s0 += __shfl_xor(s0, 8); s1 += __shfl_xor(s1, 8);
      float sc0 = do_norm ? (1.f / fmaxf(sqrtf(s0), 1e-12f)) : 1.f;
      float sc1 = do_norm ? (1.f / fmaxf(sqrtf(s1), 1e-12f)) : 1.f;
      int row = m0 + w * 32 + mi * 16 + quad * 4 + r;
      if (row < Mg) {
#pragma unroll
        for (int ni = 0; ni < 8; ++ni)
          Y[(size_t)row * QKVN + n0 + ni * 16 + mn] =
              (_Float16)(acc[mi][ni][r] * (ni < 4 ? sc0 : sc1));
      }
    }
  }
}

// ---------------- attention: swapped-operand MFMA version. Block = (b, window); wave = head. ----------------
__device__ inline const _Float16* token_row_ptr(int j, int wy, int wx, int b,
                                                const _Float16* q0, const _Float16* q1,
                                                const _Float16* q2) {
  if (j >= NT) return nullptr;
  int k_, s_, p_, Hl, t; const _Float16* base;
  if (j < 25)      { k_ = 5; s_ = 4; p_ = 2; Hl = 80; t = j;      base = q0; }
  else if (j < 34) { k_ = 3; s_ = 2; p_ = 1; Hl = 40; t = j - 25; base = q1; }
  else             { k_ = 1; s_ = 1; p_ = 0; Hl = 20; t = 0;      base = q2; }
  int ty = t / k_, tx = t % k_;
  int y = wy * s_ + ty - p_;
  int x = wx * s_ + tx - p_;
  if ((unsigned)y >= (unsigned)Hl || (unsigned)x >= (unsigned)Hl) return nullptr;
  return base + ((size_t)b * Hl * Hl + (size_t)y * Hl + x) * QKVN;
}

__global__ __launch_bounds__(256, 4) void attn_kernel(const _Float16* __restrict__ qkv0,
                                                      const _Float16* __restrict__ qkv1,
                                                      const _Float16* __restrict__ qkv2,
                                                      const float* __restrict__ pos,
                                                      _Float16* __restrict__ O) {
  const int blk = blockIdx.x;               // b*NWIN + w
  const int w   = blk % NWIN;
  const int b   = blk / NWIN;
  const int wy = w / 20, wx = w % 20;
  const int tid  = threadIdx.x;
  const int h    = tid >> 6;                // wave = head
  const int lane = tid & 63;
  const int i16  = lane & 15;
  const int q4   = lane >> 4;

  __shared__ __align__(16) _Float16 vrows[48][260];   // V row-major, all heads; rows 35..47 zero

  // --- cooperative V staging: 1536 half8-chunks = 48 rows x 32 chunks over 256 threads
#pragma unroll
  for (int e0 = 0; e0 < 1536; e0 += 256) {
    int e = e0 + tid;
    int j = e >> 5, cc = e & 31;
    half8v val = (half8v)(_Float16)0.f;
    if (j < NT) {
      const _Float16* rp = token_row_ptr(j, wy, wx, b, qkv0, qkv1, qkv2);
      if (rp) val = *(const half8v*)(rp + 512 + cc * 8);
    }
    *(half8v*)&vrows[j][cc * 8] = val;
  }

  // --- Q/K fragments direct from global: tile t rows = tokens t*16 + i16
  half8v qf[3][2], kf[3][2];
#pragma unroll
  for (int t = 0; t < 3; ++t) {
    const _Float16* rp = token_row_ptr(t * 16 + i16, wy, wx, b, qkv0, qkv1, qkv2);
#pragma unroll
    for (int kc = 0; kc < 2; ++kc) {
      if (rp) {
        qf[t][kc] = *(const half8v*)(rp + h * HD + kc * 32 + q4 * 8);
        kf[t][kc] = *(const half8v*)(rp + 256 + h * HD + kc * 32 + q4 * 8);
      } else {
        qf[t][kc] = (half8v)(_Float16)0.f;
        kf[t][kc] = (half8v)(_Float16)0.f;
      }
    }
  }

  // --- swapped QK^T: s[tj][ti][r] = S^T[j=tj*16+q4*4+r][i=ti*16+i16]
  floatx4 s[3][3] = {};
#pragma unroll
  for (int kc = 0; kc < 2; ++kc)
#pragma unroll
    for (int tj = 0; tj < 3; ++tj)
#pragma unroll
      for (int ti = 0; ti < 3; ++ti)
        s[tj][ti] = __builtin_amdgcn_mfma_f32_16x16x32_f16(kf[tj][kc], qf[ti][kc], s[tj][ti], 0, 0, 0);

  // --- pos bias + tile-pad mask (j >= NT -> -inf; tj=0 rows are never masked so max stays finite)
#pragma unroll
  for (int tj = 0; tj < 3; ++tj)
#pragma unroll
    for (int ti = 0; ti < 3; ++ti)
#pragma unroll
      for (int r = 0; r < 4; ++r) {
        int j = tj * 16 + q4 * 4 + r;
        int i = ti * 16 + i16;
        if (j < NT) { if (i < NT) s[tj][ti][r] += pos[(h * NT + i) * NT + j]; }
        else s[tj][ti][r] = -INFINITY;
      }

  // --- in-register softmax over j per query i (col i16): 12 local regs + shfl_xor 16/32
  half4v pa[3][3];   // [tj][ti] = A-frag of P for PV (16x16x16 layout)
#pragma unroll
  for (int ti = 0; ti < 3; ++ti) {
    float m = s[0][ti][0];
#pragma unroll
    for (int tj = 0; tj < 3; ++tj)
#pragma unroll
      for (int r = 0; r < 4; ++r) m = fmaxf(m, s[tj][ti][r]);
    m = fmaxf(m, __shfl_xor(m, 16));
    m = fmaxf(m, __shfl_xor(m, 32));
    float sum = 0.f;
#pragma unroll
    for (int tj = 0; tj < 3; ++tj)
#pragma unroll
      for (int r = 0; r < 4; ++r) { float e = expf(s[tj][ti][r] - m); s[tj][ti][r] = e; sum += e; }
    sum += __shfl_xor(sum, 16);
    sum += __shfl_xor(sum, 32);
    float inv = 1.f / sum;
#pragma unroll
    for (int tj = 0; tj < 3; ++tj)
#pragma unroll
      for (int r = 0; r < 4; ++r) pa[tj][ti][r] = (_Float16)(s[tj][ti][r] * inv);
  }

  __syncthreads();   // vrows ready for all waves

  // --- V B-frags for 16x16x16: lane holds V[j=tj*16+q4*4+kk][d=n*16+i16] (this head's cols)
  half4v vb[3][4];
#pragma unroll
  for (int tj = 0; tj < 3; ++tj)
#pragma unroll
    for (int n = 0; n < 4; ++n)
#pragma unroll
      for (int kk = 0; kk < 4; ++kk)
        vb[tj][n][kk] = vrows[tj * 16 + q4 * 4 + kk][h * HD + n * 16 + i16];

  // --- PV: O[i][d] accumulated over 3 j-chunks of 16; C layout row=q4*4+r (i), col=i16 (d)
  const size_t obase = ((size_t)(b * NWIN + w) * NT) * C + h * HD;
#pragma unroll
  for (int ti = 0; ti < 3; ++ti) {
    floatx4 o[4] = {};
#pragma unroll
    for (int tj = 0; tj < 3; ++tj)
#pragma unroll
      for (int n = 0; n < 4; ++n)
        o[n] = __builtin_amdgcn_mfma_f32_16x16x16f16(pa[tj][ti], vb[tj][n], o[n], 0, 0, 0);
#pragma unroll
    for (int r = 0; r < 4; ++r) {
      int i = ti * 16 + q4 * 4 + r;
      if (i < NT) {
#pragma unroll
        for (int n = 0; n < 4; ++n)
          O[obase + (size_t)i * C + n * 16 + i16] = (_Float16)o[n][r];
      }
    }
  }
}

// ---------------- proj GEMM (f16 MFMA, reg-prefetch) + bias, transposed store ----------------
__global__ __launch_bounds__(256) void proj_gemm(const _Float16* __restrict__ A,  // (Mg, 256) f16 row-major
                                                 const float* __restrict__ W,     // (256, 256) row-major
                                                 const float* __restrict__ bias,
                                                 float* __restrict__ Yt, int Mg) {
  __shared__ __align__(16) char smem[128 * 69 * 4];   // max(As+Bs = 15360, Cs = 35328)
  _Float16 (*As)[40] = (_Float16(*)[40])smem;
  _Float16 (*Bs)[40] = (_Float16(*)[40])(smem + 128 * 40 * 2);
  float    (*Cs)[69] = (float(*)[69])smem;

  const int tid  = threadIdx.x;
  const int m0   = blockIdx.x * 128;
  const int n0   = blockIdx.y * 64;
  const int w    = tid >> 6;
  const int lane = tid & 63;
  const int quad = lane >> 4;
  const int mn   = lane & 15;

  int aM[2], aK8[2], aRow[2];
#pragma unroll
  for (int u = 0; u < 2; ++u) {
    int e = u * 256 + tid;           // 512 units: 128 m x 4 k-octs
    aM[u] = e >> 2; aK8[u] = e & 3;
    aRow[u] = min(m0 + aM[u], Mg - 1);
  }

  half8v apre[2]; float bpre[8];
  auto PLOAD = [&](int k0) {
#pragma unroll
    for (int u = 0; u < 2; ++u)
      apre[u] = *(const half8v*)&A[(size_t)aRow[u] * C + k0 + 8 * aK8[u]];
    const float* wp = W + (size_t)(k0 + w * 8) * C + n0 + lane;
#pragma unroll
    for (int j = 0; j < 8; ++j) bpre[j] = wp[(size_t)j * C];
  };

  PLOAD(0);
  floatx4 acc[2][4] = {};
  for (int k0 = 0; k0 < C; k0 += 32) {
#pragma unroll
    for (int u = 0; u < 2; ++u) *(half8v*)&As[aM[u]][8 * aK8[u]] = apre[u];
    {
      half8v hv;
#pragma unroll
      for (int j = 0; j < 8; ++j) hv[j] = (_Float16)bpre[j];
      *(half8v*)&Bs[lane][w * 8] = hv;
    }
    __syncthreads();
    if (k0 + 32 < C) PLOAD(k0 + 32);   // prefetch next K-step under MFMA
    half8v a0 = *(const half8v*)&As[w * 32 + mn][quad * 8];
    half8v a1 = *(const half8v*)&As[w * 32 + 16 + mn][quad * 8];
#pragma unroll
    for (int ni = 0; ni < 4; ++ni) {
      half8v bf = *(const half8v*)&Bs[ni * 16 + mn][quad * 8];
      acc[0][ni] = __builtin_amdgcn_mfma_f32_16x16x32_f16(a0, bf, acc[0][ni], 0, 0, 0);
      acc[1][ni] = __builtin_amdgcn_mfma_f32_16x16x32_f16(a1, bf, acc[1][ni], 0, 0, 0);
    }
    __syncthreads();   // also protects As/Bs before Cs aliasing overwrite
  }

  // epilogue: bias add into Cs, then transposed coalesced store
#pragma unroll
  for (int mi = 0; mi < 2; ++mi)
#pragma unroll
    for (int r = 0; r < 4; ++r)
#pragma unroll
      for (int ni = 0; ni < 4; ++ni)
        Cs[w * 32 + mi * 16 + quad * 4 + r][ni * 16 + mn] =
            acc[mi][ni][r] + bias[n0 + ni * 16 + mn];
  __syncthreads();
#pragma unroll
  for (int u = 0; u < 32; ++u) {
    int e = u * 256 + tid;            // 8192 elems: 128 m x 64 n
    int ml = e & 127, cl = e >> 7;
    int m = m0 + ml;
    if (m < Mg) {
      int bb = m / RPB;
      int r = m - bb * RPB;
      Yt[((size_t)bb * C + n0 + cl) * RPB + r] = Cs[ml][cl];
    }
  }
}

// ---------------- fold (gather form), group-local ----------------
__global__ __launch_bounds__(256) void fold_kernel(const float* __restrict__ Yt,
                                                   float* __restrict__ out,
                                                   int k_, int s_, int p_, int H_,
                                                   int toff, int total) {
  int idx = blockIdx.x * 256 + threadIdx.x;
  if (idx >= total) return;
  int x = idx % H_;
  int y = (idx / H_) % H_;
  int c = (idx / (H_ * H_)) % C;
  int b = idx / (C * H_ * H_);
  int py = y + p_, px = x + p_;
  int ay = py - k_ + 1;
  int wy_lo = ay <= 0 ? 0 : (ay + s_ - 1) / s_;
  int wy_hi = min(19, py / s_);
  int ax = px - k_ + 1;
  int wx_lo = ax <= 0 ? 0 : (ax + s_ - 1) / s_;
  int wx_hi = min(19, px / s_);
  const float* base = Yt + ((size_t)b * C + c) * RPB;
  float acc = 0.f;
  for (int wy = wy_lo; wy <= wy_hi; ++wy) {
    int tyy = py - wy * s_;
    for (int wx = wx_lo; wx <= wx_hi; ++wx) {
      int txx = px - wx * s_;
      acc += base[(wy * 20 + wx) * NT + toff + tyy * k_ + txx];
    }
  }
  out[idx] = acc;
}

} // namespace

extern "C" void kernel_launch(void* const* d_in, const int* in_sizes, int n_in,
                              void* d_out, int out_size, void* d_ws, size_t ws_size,
                              hipStream_t stream) {
  const float* x0    = (const float*)d_in[0];
  const float* x1    = (const float*)d_in[1];
  const float* x2    = (const float*)d_in[2];
  const float* wq0   = (const float*)d_in[3];
  const float* wq1   = (const float*)d_in[4];
  const float* wq2   = (const float*)d_in[5];
  const float* wproj = (const float*)d_in[6];
  const float* bproj = (const float*)d_in[7];
  const float* rpb   = (const float*)d_in[8];
  const float* ab    = (const float*)d_in[9];
  float* out = (float*)d_out;

  // pick largest batch-group size g in {8,4,2,1} that fits ws_size
  int g = 8;
  while (g > 1 && POS_B + (size_t)g * PB_B > ws_size) g >>= 1;

  char* ws = (char*)d_ws;
  float*    posb  = (float*)ws;
  _Float16* qkv0g = (_Float16*)(ws + POS_B);
  _Float16* qkv1g = qkv0g + (size_t)g * 6400 * QKVN;
  _Float16* qkv2g = qkv1g + (size_t)g * 1600 * QKVN;
  _Float16* oatt  = qkv2g + (size_t)g *  400 * QKVN;
  float*    yt    = (float*)(ws + POS_B + (size_t)g * (QKV_B + OATT_B));

  pos_kernel<<<(NH * NT * NT + 255) / 256, 256, 0, stream>>>(rpb, ab, posb);

  const size_t off1 = (size_t)B * C * 6400;
  const size_t off2 = off1 + (size_t)B * C * 1600;

  const int mb0 = (g * 6400 + 127) / 128;
  const int mb1 = (g * 1600 + 127) / 128;
  const int mb2 = (g *  400 + 127) / 128;

  for (int b0 = 0; b0 < B; b0 += g) {
    const float* x0g = x0 + (size_t)b0 * C * 6400;
    const float* x1g = x1 + (size_t)b0 * C * 1600;
    const float* x2g = x2 + (size_t)b0 * C * 400;

    qkv_gemm<<<dim3(mb0 + mb1 + mb2, QKVN / 128), 256, 0, stream>>>(
        x0g, x1g, x2g, wq0, wq1, wq2, qkv0g, qkv1g, qkv2g, mb0, mb0 + mb1, g);

    attn_kernel<<<g * NWIN, 256, 0, stream>>>(qkv0g, qkv1g, qkv2g, posb, oatt);

    proj_gemm<<<dim3((g * RPB + 127) / 128, C / 64), 256, 0, stream>>>(oatt, wproj, bproj, yt, g * RPB);

    const int tot0 = g * C * 6400;
    const int tot1 = g * C * 1600;
    const int tot2 = g * C * 400;
    fold_kernel<<<(tot0 + 255) / 256, 256, 0, stream>>>(yt, out + (size_t)b0 * C * 6400,        5, 4, 2, 80, 0,  tot0);
    fold_kernel<<<(tot1 + 255) / 256, 256, 0, stream>>>(yt, out + off1 + (size_t)b0 * C * 1600, 3, 2, 1, 40, 25, tot1);
    fold_kernel<<<(tot2 + 255) / 256, 256, 0, stream>>>(yt, out + off2 + (size_t)b0 * C * 400,  1, 1, 0, 20, 34, tot2);
  }
}